// Round 9
// baseline (508.430 us; speedup 1.0000x reference)
//
#include <hip/hip_runtime.h>
#include <math.h>

#define NN 1024
#define NNP 1025
#define DD 256
#define CC 5
#define G3 768
#define MAXT 512
#define NA 70
#define PW3 176

typedef _Float16 v8h __attribute__((ext_vector_type(8)));
typedef _Float16 v4h __attribute__((ext_vector_type(4)));
typedef float v4f __attribute__((ext_vector_type(4)));
typedef int v4i __attribute__((ext_vector_type(4)));

__device__ __forceinline__ int scale_of(int a){ return (a<15)?0:((a<55)?1:2); }
__device__ __forceinline__ int off_of(int s){ return (s==0)?0:((s==1)?15:55); }

__device__ __forceinline__ float sigf(float x){ return __fdividef(1.f, 1.f + __expf(-x)); }
__device__ __forceinline__ float tanhf_fast(float x){ return 1.f - __fdividef(2.f, __expf(2.f*x) + 1.f); }

// ---------------- PREP mega-kernel ----------------
// blocks 0..3      : abn = softmax(node_pred)[:,0]
// blocks 4..73     : per-anchor stable gather (order/cnteff)
// blocks 74..82    : absmax -> qs (9 MLP matrices, one block each)
// blocks 83..1234  : whh per-column absmax (4 rows/block, 1 wave/row)
// blocks 1235..1252: fill fake bias row NN of E
// blocks 1253..1508: emb -> fp16
// blocks 1509..2084: wih -> fp16 MFMA B-fragments
__global__ __launch_bounds__(256) void prep_kernel(
    const float* __restrict__ node_pred, const float* __restrict__ tp_in,
    const float* __restrict__ audio_len, const float* __restrict__ anchors,
    const float* __restrict__ whh, const float* __restrict__ wih,
    const float* __restrict__ emb,
    const float* __restrict__ bih, const float* __restrict__ bhh,
    const float* __restrict__ w1, const float* __restrict__ w2,
    const float* __restrict__ w30, const float* __restrict__ w31, const float* __restrict__ w32,
    float* __restrict__ abn, int* __restrict__ order, int* __restrict__ cnteff,
    float* __restrict__ qs, float* __restrict__ cm, _Float16* __restrict__ E,
    _Float16* __restrict__ emb16, v8h* __restrict__ wihB){
  int b = blockIdx.x, tid = threadIdx.x;
  if (b < 4){
    int i = b*256 + tid;
    float pv[CC]; float m = -1e30f;
    for (int c=0;c<CC;++c){ pv[c]=node_pred[i*CC+c]; m=fmaxf(m,pv[c]); }
    float s=0.f;
    for (int c=0;c<CC;++c) s += expf(pv[c]-m);
    abn[i] = expf(pv[0]-m)/s;
  } else if (b < 74){
    if (tid >= 64) return;
    int a = b-4; int lane = tid;
    float al = audio_len[0];
    float s = anchors[2*a], e = anchors[2*a+1];
    int* ord = order + a*MAXT;
    int cnt = 0;
    for (int base=0; base<NN; base+=64){
      float tp = tp_in[base+lane]*al;
      bool msk = (tp>=s)&&(tp<=e);
      unsigned long long bal = __ballot(msk);
      int off = (int)__popcll(bal & ((1ull<<lane)-1ull));
      if (msk && (cnt+off)<MAXT) ord[cnt+off] = base+lane;
      cnt += (int)__popcll(bal);
    }
    if (lane==0){ int c = cnt<MAXT?cnt:MAXT; cnteff[2*a]=c; cnteff[2*a+1]=(c>0)?c:1; }
  } else if (b < 83){
    int m = b-74;
    const float* p; int n;
    if (m<3){ p = w1 + (size_t)m*256*519; n = 256*519; }
    else if (m<6){ p = w2 + (size_t)(m-3)*256*256; n = 256*256; }
    else { p = (m==6)?w30:((m==7)?w31:w32); n = ((m==7)?125:165)*256; }
    float mx = 0.f;
    for (int i=tid;i<n;i+=256) mx = fmaxf(mx, fabsf(p[i]));
    __shared__ float red[256];
    red[tid]=mx; __syncthreads();
    for (int sft=128; sft>0; sft>>=1){ if (tid<sft) red[tid]=fmaxf(red[tid],red[tid+sft]); __syncthreads(); }
    if (tid==0) qs[m] = fmaxf(red[0]/127.f, 1e-8f);
  } else if (b < 1235){
    int row = (b-83)*4 + (tid>>6);
    int lane = tid&63;
    float4 v = reinterpret_cast<const float4*>(whh)[(size_t)row*64 + lane];
    float mx = fmaxf(fmaxf(fabsf(v.x),fabsf(v.y)), fmaxf(fabsf(v.z),fabsf(v.w)));
    #pragma unroll
    for (int sh=1; sh<64; sh<<=1) mx = fmaxf(mx, __shfl_xor(mx, sh));
    if (lane==0) cm[row] = fmaxf(mx, 1e-12f);
  } else if (b < 1253){
    int i = (b-1235)*256 + tid;           // 6*256*3 = 4608
    if (i >= 4608) return;
    int gt = i % 3; int c = (i/3)&255; int sd = i/768;
    int j = gt*256 + c;
    float v = bih[sd*G3+j] + ((gt<2)? bhh[sd*G3+j] : 0.f);
    E[((size_t)(sd*NNP + NN))*1024 + c*4 + gt] = (_Float16)v;
  } else if (b < 1509){
    int i = (b-1253)*256 + tid;           // 65536 float4's
    float4 v = reinterpret_cast<const float4*>(emb)[i];
    v4h o; o[0]=(_Float16)v.x; o[1]=(_Float16)v.y; o[2]=(_Float16)v.z; o[3]=(_Float16)v.w;
    *reinterpret_cast<v4h*>(emb16 + (size_t)i*4) = o;
  } else {
    int i = (b-1509)*256 + tid;           // 6*48*64*8 = 147456
    int q    = i & 7;
    int lane = (i>>3) & 63;
    int ct   = (i>>9) % 48;
    int sd   = i / 24576;
    int j = ct*16 + (lane&15);
    int k0 = 32*q + 8*(lane>>4);
    const float* src = wih + ((size_t)sd*G3 + j)*DD + k0;
    v8h o;
    #pragma unroll
    for (int e2=0;e2<8;++e2) o[e2] = (_Float16)src[e2];
    wihB[i] = o;
  }
}

// ---------------- QUANT kernel ----------------
__global__ __launch_bounds__(256) void quant_kernel(
    const float* __restrict__ whh, const float* __restrict__ cm,
    const float* __restrict__ w1, const float* __restrict__ w2,
    const float* __restrict__ w30, const float* __restrict__ w31, const float* __restrict__ w32,
    const float* __restrict__ qs,
    uint4* __restrict__ whhB8, float* __restrict__ w1T, float* __restrict__ w2T, float* __restrict__ w3T){
  int b = blockIdx.x, tid = threadIdx.x;
  if (b < 288){
    int i = b*256 + tid;                  // < 6*8*64*24 = 73728
    int q    = i & 3;
    int nt   = (i>>2) % 6;
    int lane = (i/24) & 63;
    int wv   = (i/1536) & 7;
    int sd   = i/12288;
    int gt = nt>>1, half = nt&1;
    int j = gt*256 + wv*32 + half*16 + (lane&15);
    int kbase = 64*q + 16*(lane>>4);
    float inv = 127.f/cm[sd*G3 + j];
    const float* src = whh + ((size_t)sd*G3 + j)*DD + kbase;
    unsigned int dw[4];
    #pragma unroll
    for (int d2=0; d2<4; ++d2){
      unsigned int acc = 0;
      #pragma unroll
      for (int e2=0; e2<4; ++e2){
        float qv = rintf(src[4*d2+e2]*inv);
        qv = fminf(fmaxf(qv,-127.f),127.f);
        int iq = (int)qv;
        acc |= ((unsigned int)(iq & 255)) << (8*e2);
      }
      dw[d2] = acc;
    }
    uint4 v; v.x=dw[0]; v.y=dw[1]; v.z=dw[2]; v.w=dw[3];
    whhB8[i] = v;
  } else if (b < 1056){
    int row = b-288; int si = row>>8; int j = row&255;
    float sc = qs[si];
    const float* src = w1 + ((size_t)si*256 + j)*519;
    #pragma unroll
    for (int it=0; it<3; ++it){
      int k = it*256 + tid;
      if (k >= 520) break;
      float v = 0.f;
      if (k < 519){
        float q = rintf(src[k]/sc);
        q = fminf(fmaxf(q,-128.f),127.f);
        v = q*sc;
      }
      w1T[((size_t)si*520 + k)*256 + j] = v;
    }
  } else if (b < 1824){
    int row = b-1056; int si = row>>8; int j = row&255;
    float sc = qs[3+si];
    const float* src = w2 + ((size_t)si*256 + j)*256;
    float q = rintf(src[tid]/sc);
    q = fminf(fmaxf(q,-128.f),127.f);
    w2T[((size_t)si*256 + tid)*256 + j] = q*sc;
  } else {
    int row = b-1824; int si = row/PW3; int j = row%PW3;
    int nout = (si==1)?125:165;
    const float* w3 = (si==0)?w30:((si==1)?w31:w32);
    float v = 0.f;
    if (j < nout){
      float sc = qs[6+si];
      float q = rintf(w3[(size_t)j*256 + tid]/sc);
      q = fminf(fmaxf(q,-128.f),127.f);
      v = q*sc;
    }
    w3T[((size_t)si*256 + tid)*PW3 + j] = v;
  }
}

// ---------------- E-GEMM via MFMA fp16: one wave per 16x16 output tile, K=256 ----------------
__global__ __launch_bounds__(256) void e_gemm(const _Float16* __restrict__ emb16,
                       const v8h* __restrict__ wihB,
                       const float* __restrict__ bih, const float* __restrict__ bhh,
                       _Float16* __restrict__ E){
  int sd = blockIdx.z;
  int tid = threadIdx.x;
  int w = tid>>6, lane = tid&63;
  int tile = blockIdx.x*4 + w;            // 0..3071
  int r_t = tile & 63, c_t = tile >> 6;
  int row0 = r_t*16, col0 = c_t*16;
  int j = col0 + (lane&15);               // this lane's output column
  float bsum = bih[sd*G3 + j] + (((j>>8) < 2) ? bhh[sd*G3 + j] : 0.f);

  const _Float16* A = emb16 + (size_t)(row0 + (lane&15))*DD + 8*(lane>>4);
  const v8h* B = wihB + (((size_t)sd*48 + c_t)*64 + lane)*8;

  v4f acc = {0.f,0.f,0.f,0.f};
  #pragma unroll
  for (int q=0;q<8;++q){
    v8h af = *reinterpret_cast<const v8h*>(A + 32*q);
    acc = __builtin_amdgcn_mfma_f32_16x16x32_f16(af, B[q], acc, 0,0,0);
  }
  int gt = j>>8, c = j&255;
  #pragma unroll
  for (int r=0;r<4;++r){
    int row = row0 + (lane>>4)*4 + r;
    E[((size_t)(sd*NNP + row))*1024 + c*4 + gt] = (_Float16)(acc[r] + bsum);
  }
}

// ---------------- GRU: int8 MFMA 16x16x64, 1 cell/lane, 8B/lane E loads ----------------
__global__ __launch_bounds__(512, 2) void gru_kernel(
                           const _Float16* __restrict__ E, const v4i* __restrict__ whhB8,
                           const float* __restrict__ bhh, const float* __restrict__ cm,
                           const int* __restrict__ order, const int* __restrict__ cnteff,
                           float* __restrict__ hout){
  int a = blockIdx.x>>1, d = blockIdx.x&1;
  int si = scale_of(a);
  int sd = si*2+d;
  int tid = threadIdx.x;
  int w = tid>>6, lane = tid&63;
  int g16 = lane>>4;
  int ct = g16 & 1;

  __shared__ int ord_s[MAXT];
  __shared__ alignas(16) signed char h8[2][DD];

  ord_s[tid] = order[a*MAXT + tid];
  if (tid < DD) h8[0][tid] = 0;

  int cnt = cnteff[2*a], eff = cnteff[2*a+1];

  int c = w*32 + (lane&31);                 // this lane's cell
  float bn = bhh[sd*G3 + 2*DD + c];
  const float ISQ = 1.f/(127.f*127.f);
  float sr = cm[sd*G3 +        c]*ISQ;
  float sz = cm[sd*G3 + 256 +  c]*ISQ;
  float sn = cm[sd*G3 + 512 +  c]*ISQ;

  v4i bf[6][4];
  {
    const v4i* wp = whhB8 + (((size_t)sd*8 + w)*64 + lane)*24;
    #pragma unroll
    for (int nt=0;nt<6;++nt)
      #pragma unroll
      for (int q=0;q<4;++q)
        bf[nt][q] = wp[nt*4+q];
  }

  const uint2* Eb = reinterpret_cast<const uint2*>(E) + (size_t)sd*NNP*256;

  float h = 0.f;
  uint2 gEven, gOdd;
  {
    int idx0 = d ? (eff-1) : 0;
    int n0 = (idx0 < cnt) ? ord_s[idx0] : NN;
    gEven = Eb[(size_t)n0*256 + c];
  }
  __syncthreads();

  for (int t=0;t<eff;++t){
    int p = t & 1;
    if (t+1 < eff){
      int idx1 = d ? (eff-2-t) : (t+1);
      int n1 = (idx1 < cnt) ? ord_s[idx1] : NN;
      if (p==0) gOdd  = Eb[(size_t)n1*256 + c];
      else      gEven = Eb[(size_t)n1*256 + c];
    }
    v4i acc0={0,0,0,0}, acc1={0,0,0,0}, acc2={0,0,0,0};
    v4i acc3={0,0,0,0}, acc4={0,0,0,0}, acc5={0,0,0,0};
    #pragma unroll
    for (int q=0;q<4;++q){
      v4i af = *reinterpret_cast<const v4i*>(&h8[p][64*q + 16*g16]);
      acc0 = __builtin_amdgcn_mfma_i32_16x16x64_i8(af, bf[0][q], acc0, 0,0,0);
      acc1 = __builtin_amdgcn_mfma_i32_16x16x64_i8(af, bf[1][q], acc1, 0,0,0);
      acc2 = __builtin_amdgcn_mfma_i32_16x16x64_i8(af, bf[2][q], acc2, 0,0,0);
      acc3 = __builtin_amdgcn_mfma_i32_16x16x64_i8(af, bf[3][q], acc3, 0,0,0);
      acc4 = __builtin_amdgcn_mfma_i32_16x16x64_i8(af, bf[4][q], acc4, 0,0,0);
      acc5 = __builtin_amdgcn_mfma_i32_16x16x64_i8(af, bf[5][q], acc5, 0,0,0);
    }
    v4h ev = __builtin_bit_cast(v4h, (p==0) ? gEven : gOdd);
    int ir  = (ct==0) ? acc0[0] : acc1[0];
    int iz  = (ct==0) ? acc2[0] : acc3[0];
    int inn = (ct==0) ? acc4[0] : acc5[0];
    float r  = sigf((float)ev[0] + (float)ir*sr);
    float z  = sigf((float)ev[1] + (float)iz*sz);
    float nv = tanhf_fast((float)ev[2] + r*((float)inn*sn + bn));
    h = z*(h - nv) + nv;
    if (lane < 32) h8[p^1][c] = (signed char)(int)rintf(h*127.f);
    __syncthreads();
  }
  if (lane < 32) hout[(size_t)(2*a+d)*DD + c] = h;
}

// ---------------- MLP + head ----------------
__global__ __launch_bounds__(256) void mlp_kernel(const float* __restrict__ hout, const float* __restrict__ abn,
                           const float* __restrict__ anchors, const float* __restrict__ audio_len,
                           const float* __restrict__ w1T, const float* __restrict__ w2T,
                           const float* __restrict__ w3T,
                           const float* __restrict__ sw0, const float* __restrict__ ew0,
                           const float* __restrict__ sw1, const float* __restrict__ ew1,
                           const float* __restrict__ sw2, const float* __restrict__ ew2,
                           float* __restrict__ out){
  int a = blockIdx.x, tid = threadIdx.x;
  int si = scale_of(a);
  int il = a - off_of(si);
  float s = anchors[2*a], e = anchors[2*a+1];
  float al = audio_len[0];
  __shared__ float feat[520];
  __shared__ float h1[256], h2[256], o[PW3];
  feat[tid]    = hout[(size_t)(2*a+0)*DD + tid];
  feat[DD+tid] = hout[(size_t)(2*a+1)*DD + tid];
  if (tid==0){
    feat[512]=abn[il];
    feat[513]=(s+e)*0.5f/al;
    feat[514]=(e-s)/al;
    feat[515]=0.f; feat[516]=0.f; feat[517]=0.f; feat[518]=0.f; feat[519]=0.f;
  }
  __syncthreads();
  {
    const float* p1 = w1T + (size_t)si*520*256 + tid;
    float acc=0.f;
    #pragma unroll 4
    for (int k=0;k<519;++k) acc += feat[k]*p1[(size_t)k*256];
    h1[tid]=fmaxf(acc,0.f);
  }
  __syncthreads();
  {
    const float* p2 = w2T + (size_t)si*256*256 + tid;
    float acc=0.f;
    #pragma unroll 4
    for (int k=0;k<256;++k) acc += h1[k]*p2[(size_t)k*256];
    h2[tid]=fmaxf(acc,0.f);
  }
  __syncthreads();
  if (tid<PW3){
    const float* p3 = w3T + (size_t)si*256*PW3 + tid;
    float acc=0.f;
    #pragma unroll 4
    for (int k=0;k<256;++k) acc += h2[k]*p3[(size_t)k*PW3];
    o[tid]=acc;
  }
  __syncthreads();
  if (tid==0){
    int b = (si==1)?60:80;
    const float* sw = (si==0)?sw0:((si==1)?sw1:sw2);
    const float* ew = (si==0)?ew0:((si==1)?ew1:ew2);
    float m=-1e30f; for (int i=0;i<b;++i) m=fmaxf(m,o[i]);
    float se=0.f, wsum=0.f;
    for (int i=0;i<b;++i){ float t=expf(o[i]-m); se+=t; wsum+=t*sw[i]; }
    float so = wsum/se;
    m=-1e30f; for (int i=0;i<b;++i) m=fmaxf(m,o[b+i]);
    se=0.f; wsum=0.f;
    for (int i=0;i<b;++i){ float t=expf(o[b+i]-m); se+=t; wsum+=t*ew[i]; }
    float eo = wsum/se;
    out[2*a]   = fminf(fmaxf(s+so,0.f),al);
    out[2*a+1] = fminf(fmaxf(e+eo,0.f),al);
    out[140+a] = o[2*b];
    for (int c2=0;c2<4;++c2) out[210+4*a+c2] = o[2*b+1+c2];
  }
}

extern "C" void kernel_launch(void* const* d_in, const int* in_sizes, int n_in,
                              void* d_out, int out_size, void* d_ws, size_t ws_size,
                              hipStream_t stream){
  const float* emb   = (const float*)d_in[0];
  const float* tpin  = (const float*)d_in[1];
  const float* npred = (const float*)d_in[2];
  const float* alen  = (const float*)d_in[3];
  const float* anch  = (const float*)d_in[4];
  const float* wih   = (const float*)d_in[5];
  const float* whh   = (const float*)d_in[6];
  const float* bih   = (const float*)d_in[7];
  const float* bhh   = (const float*)d_in[8];
  const float* w1    = (const float*)d_in[9];
  const float* w2    = (const float*)d_in[10];
  const float* w30   = (const float*)d_in[11];
  const float* w31   = (const float*)d_in[12];
  const float* w32   = (const float*)d_in[13];
  const float* sw0   = (const float*)d_in[14];
  const float* ew0   = (const float*)d_in[15];
  const float* sw1   = (const float*)d_in[16];
  const float* ew1   = (const float*)d_in[17];
  const float* sw2   = (const float*)d_in[18];
  const float* ew2   = (const float*)d_in[19];

  char* ws = (char*)d_ws;
  size_t off = 0;
  auto take = [&](size_t bytes)->char*{
    char* p = ws + off;
    off = (off + bytes + 255) & ~(size_t)255;
    return p;
  };
  float* abn    = (float*)take((size_t)NN*4);
  int*   order_ = (int*)  take((size_t)NA*MAXT*4);
  int*   cnteff = (int*)  take((size_t)NA*2*4);
  float* qs     = (float*)take(16*4);
  float* cm     = (float*)take((size_t)6*G3*4);
  v4i*   whhB8  = (v4i*)  take((size_t)6*8*64*24*16);
  _Float16* E   = (_Float16*)take((size_t)6*NNP*1024*2);
  float* hout   = (float*)take((size_t)NA*2*DD*4);
  float* w1T    = (float*)take((size_t)3*520*256*4);
  float* w2T    = (float*)take((size_t)3*256*256*4);
  float* w3T    = (float*)take((size_t)3*256*PW3*4);
  _Float16* emb16 = (_Float16*)take((size_t)NN*DD*2);
  v8h*   wihB   = (v8h*)take((size_t)6*48*64*8*16);
  (void)ws_size; (void)in_sizes; (void)n_in; (void)out_size;

  prep_kernel<<<dim3(2085), dim3(256), 0, stream>>>(npred, tpin, alen, anch, whh, wih, emb,
                                                    bih, bhh, w1, w2, w30, w31, w32,
                                                    abn, order_, cnteff, qs, cm, E, emb16, wihB);
  e_gemm<<<dim3(768,1,6), dim3(256), 0, stream>>>(emb16, wihB, bih, bhh, E);
  quant_kernel<<<dim3(2352), dim3(256), 0, stream>>>(whh, cm, w1, w2, w30, w31, w32, qs,
                                                     (uint4*)whhB8, w1T, w2T, w3T);
  gru_kernel<<<dim3(NA*2), dim3(512), 0, stream>>>(E, whhB8, bhh, cm, order_, cnteff, hout);
  mlp_kernel<<<dim3(NA), dim3(256), 0, stream>>>(hout, abn, anch, alen, w1T, w2T, w3T,
                                                 sw0, ew0, sw1, ew1, sw2, ew2, (float*)d_out);
}

// Round 10
// 418.637 us; speedup vs baseline: 1.2145x; 1.2145x over previous
//
#include <hip/hip_runtime.h>
#include <math.h>

#define NN 1024
#define NNP 1025
#define DD 256
#define CC 5
#define G3 768
#define MAXT 512
#define NA 70

typedef _Float16 v8h __attribute__((ext_vector_type(8)));
typedef _Float16 v4h __attribute__((ext_vector_type(4)));
typedef float v4f __attribute__((ext_vector_type(4)));
typedef int v4i __attribute__((ext_vector_type(4)));

__device__ __forceinline__ float sigf(float x){ return __fdividef(1.f, 1.f + __expf(-x)); }
__device__ __forceinline__ float tanhf_fast(float x){ return 1.f - __fdividef(2.f, __expf(2.f*x) + 1.f); }

// ================= MEGA kernel =================
// blocks [0,4)      : abn = softmax(node_pred)[:,0]
// blocks [4,74)     : per-anchor stable gather (order/cnteff)
// blocks [74,83)    : absmax -> qs (9 MLP matrices)
// blocks [83,101)   : fake bias row NN of E
// blocks [101,149)  : whh colmax (cm) + int8 MFMA B-fragments, self-contained per (sd,w)
// blocks [149,4757) : E-GEMM via MFMA fp16, direct fp32 reads with inline cvt
__global__ __launch_bounds__(256) void mega_kernel(
    const float* __restrict__ node_pred, const float* __restrict__ tp_in,
    const float* __restrict__ audio_len, const float* __restrict__ anchors,
    const float* __restrict__ whh, const float* __restrict__ wih,
    const float* __restrict__ emb,
    const float* __restrict__ bih, const float* __restrict__ bhh,
    const float* __restrict__ w1, const float* __restrict__ w2,
    const float* __restrict__ w30, const float* __restrict__ w31, const float* __restrict__ w32,
    float* __restrict__ abn, int* __restrict__ order, int* __restrict__ cnteff,
    float* __restrict__ qs, float* __restrict__ cm,
    uint4* __restrict__ whhB8, _Float16* __restrict__ E){
  __shared__ __align__(16) unsigned char smem[16*264*2];   // shared scratch, branch-local reuse
  int b = blockIdx.x, tid = threadIdx.x;
  if (b < 4){
    int i = b*256 + tid;
    float pv[CC]; float m = -1e30f;
    for (int c=0;c<CC;++c){ pv[c]=node_pred[i*CC+c]; m=fmaxf(m,pv[c]); }
    float s=0.f;
    for (int c=0;c<CC;++c) s += expf(pv[c]-m);
    abn[i] = expf(pv[0]-m)/s;
  } else if (b < 74){
    if (tid >= 64) return;
    int a = b-4; int lane = tid;
    float al = audio_len[0];
    float s = anchors[2*a], e = anchors[2*a+1];
    int* ord = order + a*MAXT;
    int cnt = 0;
    for (int base=0; base<NN; base+=64){
      float tp = tp_in[base+lane]*al;
      bool msk = (tp>=s)&&(tp<=e);
      unsigned long long bal = __ballot(msk);
      int off = (int)__popcll(bal & ((1ull<<lane)-1ull));
      if (msk && (cnt+off)<MAXT) ord[cnt+off] = base+lane;
      cnt += (int)__popcll(bal);
    }
    if (lane==0){ int c = cnt<MAXT?cnt:MAXT; cnteff[2*a]=c; cnteff[2*a+1]=(c>0)?c:1; }
  } else if (b < 83){
    int m = b-74;
    const float* p; int n;
    if (m<3){ p = w1 + (size_t)m*256*519; n = 256*519; }
    else if (m<6){ p = w2 + (size_t)(m-3)*256*256; n = 256*256; }
    else { p = (m==6)?w30:((m==7)?w31:w32); n = ((m==7)?125:165)*256; }
    float mx = 0.f;
    for (int i=tid;i<n;i+=256) mx = fmaxf(mx, fabsf(p[i]));
    float* red = (float*)smem;
    red[tid]=mx; __syncthreads();
    for (int sft=128; sft>0; sft>>=1){ if (tid<sft) red[tid]=fmaxf(red[tid],red[tid+sft]); __syncthreads(); }
    if (tid==0) qs[m] = fmaxf(red[0]/127.f, 1e-8f);
  } else if (b < 101){
    int i = (b-83)*256 + tid;             // 4608 entries
    if (i >= 4608) return;
    int gt = i % 3; int c = (i/3)&255; int sd = i/768;
    int j = gt*256 + c;
    float v = bih[sd*G3+j] + ((gt<2)? bhh[sd*G3+j] : 0.f);
    E[((size_t)(sd*NNP + NN))*1024 + c*4 + gt] = (_Float16)v;
  } else if (b < 149){
    // whh colmax + pack, per (sd, w)
    int bb = b-101;
    int sd = bb>>3, w = bb&7;
    float* cm_lds = (float*)smem;         // 96 floats
    int lane = tid & 63, wv = tid >> 6;
    // phase 1: 96 rows, 4 waves x 24 iters, coalesced float4 + shfl max
    for (int it=0; it<24; ++it){
      int lr = it*4 + wv;                 // 0..95
      int gt = lr>>5, c = lr&31;
      int j = gt*256 + w*32 + c;
      float4 v = reinterpret_cast<const float4*>(whh + ((size_t)sd*G3 + j)*DD)[lane];
      float mx = fmaxf(fmaxf(fabsf(v.x),fabsf(v.y)), fmaxf(fabsf(v.z),fabsf(v.w)));
      #pragma unroll
      for (int sh=1; sh<64; sh<<=1) mx = fmaxf(mx, __shfl_xor(mx, sh));
      if (lane==0){
        float cmax = fmaxf(mx, 1e-12f);
        cm_lds[lr] = cmax;
        cm[sd*G3 + j] = cmax;
      }
    }
    __syncthreads();
    // phase 2: pack 1536 uint4 fragments (6 per thread), reads L2-hot whh
    #pragma unroll
    for (int ee=0; ee<6; ++ee){
      int il = tid*6 + ee;                // lane2*24 + nt*4 + q
      int q    = il & 3;
      int nt   = (il>>2) % 6;
      int lane2= il / 24;
      int gt = nt>>1, half = nt&1;
      int lr = gt*32 + half*16 + (lane2&15);
      int j  = gt*256 + w*32 + half*16 + (lane2&15);
      int kbase = 64*q + 16*(lane2>>4);
      float inv = 127.f/cm_lds[lr];
      const float* src = whh + ((size_t)sd*G3 + j)*DD + kbase;
      unsigned int dw[4];
      #pragma unroll
      for (int d2=0; d2<4; ++d2){
        unsigned int acc = 0;
        #pragma unroll
        for (int e2=0; e2<4; ++e2){
          float qv = rintf(src[4*d2+e2]*inv);
          qv = fminf(fmaxf(qv,-127.f),127.f);
          int iq = (int)qv;
          acc |= ((unsigned int)(iq & 255)) << (8*e2);
        }
        dw[d2] = acc;
      }
      uint4 v; v.x=dw[0]; v.y=dw[1]; v.z=dw[2]; v.w=dw[3];
      whhB8[(size_t)(sd*8 + w)*1536 + il] = v;
    }
  } else {
    // E-GEMM: block = one row-tile (16 rows) x 4 col-tiles (4 waves); A staged in LDS fp16
    typedef _Float16 AsT[264];
    AsT* As = (AsT*)smem;                 // [16][264] fp16, padded (+8) for banks
    int b2 = b - 149;
    int sd = b2 / 768;
    int rem = b2 - sd*768;
    int r_t = rem & 63, cg = rem >> 6;    // cg 0..11
    int row0 = r_t*16;
    int lane = tid & 63, wv = tid >> 6;
    int l15 = lane & 15, g16 = lane >> 4;
    // stage A (emb fp32 -> LDS fp16)
    {
      int rr = tid>>4, k0 = (tid&15)*16;
      const float4* ep = reinterpret_cast<const float4*>(emb + (size_t)(row0+rr)*DD + k0);
      #pragma unroll
      for (int f=0; f<4; ++f){
        float4 v = ep[f];
        v4h o; o[0]=(_Float16)v.x; o[1]=(_Float16)v.y; o[2]=(_Float16)v.z; o[3]=(_Float16)v.w;
        *reinterpret_cast<v4h*>(&As[rr][k0 + f*4]) = o;
      }
    }
    __syncthreads();
    int c_t = cg*4 + wv;
    int j = c_t*16 + l15;
    const float* Bp = wih + ((size_t)sd*G3 + j)*DD + 8*g16;
    float bsum = bih[sd*G3 + j] + (((j>>8) < 2) ? bhh[sd*G3 + j] : 0.f);
    v4f acc = {0.f,0.f,0.f,0.f};
    #pragma unroll
    for (int q=0;q<8;++q){
      v8h af = *reinterpret_cast<const v8h*>(&As[l15][32*q + 8*g16]);
      float4 b0 = *reinterpret_cast<const float4*>(Bp + 32*q);
      float4 b1 = *reinterpret_cast<const float4*>(Bp + 32*q + 4);
      v8h bf;
      bf[0]=(_Float16)b0.x; bf[1]=(_Float16)b0.y; bf[2]=(_Float16)b0.z; bf[3]=(_Float16)b0.w;
      bf[4]=(_Float16)b1.x; bf[5]=(_Float16)b1.y; bf[6]=(_Float16)b1.z; bf[7]=(_Float16)b1.w;
      acc = __builtin_amdgcn_mfma_f32_16x16x32_f16(af, bf, acc, 0,0,0);
    }
    int gt = j>>8, c = j&255;
    #pragma unroll
    for (int r=0;r<4;++r){
      int row = row0 + g16*4 + r;
      E[((size_t)(sd*NNP + row))*1024 + c*4 + gt] = (_Float16)(acc[r] + bsum);
    }
  }
}

// ================= GRU (unchanged from round 8/9) =================
__global__ __launch_bounds__(512, 2) void gru_kernel(
                           const _Float16* __restrict__ E, const v4i* __restrict__ whhB8,
                           const float* __restrict__ bhh, const float* __restrict__ cm,
                           const int* __restrict__ order, const int* __restrict__ cnteff,
                           float* __restrict__ hout){
  int a = blockIdx.x>>1, d = blockIdx.x&1;
  int si = (a<15)?0:((a<55)?1:2);
  int sd = si*2+d;
  int tid = threadIdx.x;
  int w = tid>>6, lane = tid&63;
  int g16 = lane>>4;
  int ct = g16 & 1;

  __shared__ int ord_s[MAXT];
  __shared__ alignas(16) signed char h8[2][DD];

  ord_s[tid] = order[a*MAXT + tid];
  if (tid < DD) h8[0][tid] = 0;

  int cnt = cnteff[2*a], eff = cnteff[2*a+1];

  int c = w*32 + (lane&31);
  float bn = bhh[sd*G3 + 2*DD + c];
  const float ISQ = 1.f/(127.f*127.f);
  float sr = cm[sd*G3 +        c]*ISQ;
  float sz = cm[sd*G3 + 256 +  c]*ISQ;
  float sn = cm[sd*G3 + 512 +  c]*ISQ;

  v4i bf[6][4];
  {
    const v4i* wp = whhB8 + (((size_t)sd*8 + w)*64 + lane)*24;
    #pragma unroll
    for (int nt=0;nt<6;++nt)
      #pragma unroll
      for (int q=0;q<4;++q)
        bf[nt][q] = wp[nt*4+q];
  }

  const uint2* Eb = reinterpret_cast<const uint2*>(E) + (size_t)sd*NNP*256;

  float h = 0.f;
  uint2 gEven, gOdd;
  {
    int idx0 = d ? (eff-1) : 0;
    int n0 = (idx0 < cnt) ? ord_s[idx0] : NN;
    gEven = Eb[(size_t)n0*256 + c];
  }
  __syncthreads();

  for (int t=0;t<eff;++t){
    int p = t & 1;
    if (t+1 < eff){
      int idx1 = d ? (eff-2-t) : (t+1);
      int n1 = (idx1 < cnt) ? ord_s[idx1] : NN;
      if (p==0) gOdd  = Eb[(size_t)n1*256 + c];
      else      gEven = Eb[(size_t)n1*256 + c];
    }
    v4i acc0={0,0,0,0}, acc1={0,0,0,0}, acc2={0,0,0,0};
    v4i acc3={0,0,0,0}, acc4={0,0,0,0}, acc5={0,0,0,0};
    #pragma unroll
    for (int q=0;q<4;++q){
      v4i af = *reinterpret_cast<const v4i*>(&h8[p][64*q + 16*g16]);
      acc0 = __builtin_amdgcn_mfma_i32_16x16x64_i8(af, bf[0][q], acc0, 0,0,0);
      acc1 = __builtin_amdgcn_mfma_i32_16x16x64_i8(af, bf[1][q], acc1, 0,0,0);
      acc2 = __builtin_amdgcn_mfma_i32_16x16x64_i8(af, bf[2][q], acc2, 0,0,0);
      acc3 = __builtin_amdgcn_mfma_i32_16x16x64_i8(af, bf[3][q], acc3, 0,0,0);
      acc4 = __builtin_amdgcn_mfma_i32_16x16x64_i8(af, bf[4][q], acc4, 0,0,0);
      acc5 = __builtin_amdgcn_mfma_i32_16x16x64_i8(af, bf[5][q], acc5, 0,0,0);
    }
    v4h ev = __builtin_bit_cast(v4h, (p==0) ? gEven : gOdd);
    int ir  = (ct==0) ? acc0[0] : acc1[0];
    int iz  = (ct==0) ? acc2[0] : acc3[0];
    int inn = (ct==0) ? acc4[0] : acc5[0];
    float r  = sigf((float)ev[0] + (float)ir*sr);
    float z  = sigf((float)ev[1] + (float)iz*sz);
    float nv = tanhf_fast((float)ev[2] + r*((float)inn*sn + bn));
    h = z*(h - nv) + nv;
    if (lane < 32) h8[p^1][c] = (signed char)(int)rintf(h*127.f);
    __syncthreads();
  }
  if (lane < 32) hout[(size_t)(2*a+d)*DD + c] = h;
}

// ================= MLP via MFMA fp16 (quantized-integer weights, exact in fp16) =================
// 5 blocks: (si0,mt0) (si1,mt0..2) (si2,mt0). 512 threads = 8 waves.
__global__ __launch_bounds__(512) void mlp_kernel(
    const float* __restrict__ hout, const float* __restrict__ abn,
    const float* __restrict__ anchors, const float* __restrict__ audio_len,
    const float* __restrict__ w1, const float* __restrict__ w2,
    const float* __restrict__ w30, const float* __restrict__ w31, const float* __restrict__ w32,
    const float* __restrict__ qs,
    const float* __restrict__ sw0, const float* __restrict__ ew0,
    const float* __restrict__ sw1, const float* __restrict__ ew1,
    const float* __restrict__ sw2, const float* __restrict__ ew2,
    float* __restrict__ out){
  int bm = blockIdx.x;
  int si = (bm==0)?0:((bm<4)?1:2);
  int mt = (bm==0)?0:((bm<4)?(bm-1):0);
  int cntA = (si==1)?40:15;
  int offA = (si==0)?0:((si==1)?15:55);
  int nout = (si==1)?125:165;
  int bb   = (si==1)?60:80;
  int m0 = mt*16;
  const float* w3 = (si==0)?w30:((si==1)?w31:w32);
  const float* sw = (si==0)?sw0:((si==1)?sw1:sw2);
  const float* ew = (si==0)?ew0:((si==1)?ew1:ew2);
  float al = audio_len[0];

  __shared__ _Float16 feat[16][552];    // layer-1 input; reused as h2 (cols 0..255)
  __shared__ _Float16 h1s[16][264];
  __shared__ float    os[16][184];

  int tid = threadIdx.x;
  int lane = tid & 63, wv = tid >> 6;
  int l15 = lane & 15, g16 = lane >> 4;

  for (int idx = tid; idx < 16*552; idx += 512){
    int r = idx / 552, c2 = idx - r*552;
    float v = 0.f;
    int m = m0 + r;
    if (m < cntA){
      int a = offA + m;
      if (c2 < 256)       v = hout[(size_t)(2*a)*DD + c2];
      else if (c2 < 512)  v = hout[(size_t)(2*a+1)*DD + (c2-256)];
      else if (c2 == 512) v = abn[m];
      else if (c2 == 513){ float s=anchors[2*a], e=anchors[2*a+1]; v = (s+e)*0.5f/al; }
      else if (c2 == 514){ float s=anchors[2*a], e=anchors[2*a+1]; v = (e-s)/al; }
    }
    feat[r][c2] = (_Float16)v;
  }
  __syncthreads();
  float sc1 = qs[si],   inv1 = 1.f/sc1;
  float sc2 = qs[3+si], inv2 = 1.f/sc2;
  float sc3 = qs[6+si], inv3 = 1.f/sc3;

  // Layer 1: K=519 (pad 544), N=256
  for (int nt = wv; nt < 16; nt += 8){
    int j = nt*16 + l15;
    const float* Bp = w1 + ((size_t)(si*256 + j))*519;
    v4f acc = {0.f,0.f,0.f,0.f};
    for (int kq = 0; kq < 17; ++kq){
      int k0 = kq*32 + 8*g16;
      v8h af = *reinterpret_cast<const v8h*>(&feat[l15][k0]);
      v8h bf2;
      #pragma unroll
      for (int e=0;e<8;++e){
        int k = k0 + e;
        float wvv = (k < 519) ? Bp[k] : 0.f;
        float q = rintf(wvv*inv1);
        q = fminf(fmaxf(q,-128.f),127.f);
        bf2[e] = (_Float16)q;
      }
      acc = __builtin_amdgcn_mfma_f32_16x16x32_f16(af, bf2, acc, 0,0,0);
    }
    #pragma unroll
    for (int r=0;r<4;++r) h1s[g16*4+r][j] = (_Float16)fmaxf(acc[r]*sc1, 0.f);
  }
  __syncthreads();
  // Layer 2: K=256, N=256  (h2 -> feat cols 0..255)
  for (int nt = wv; nt < 16; nt += 8){
    int j = nt*16 + l15;
    const float* Bp = w2 + ((size_t)(si*256 + j))*256;
    v4f acc = {0.f,0.f,0.f,0.f};
    for (int kq = 0; kq < 8; ++kq){
      int k0 = kq*32 + 8*g16;
      v8h af = *reinterpret_cast<const v8h*>(&h1s[l15][k0]);
      v8h bf2;
      #pragma unroll
      for (int e=0;e<8;++e){
        float q = rintf(Bp[k0+e]*inv2);
        q = fminf(fmaxf(q,-128.f),127.f);
        bf2[e] = (_Float16)q;
      }
      acc = __builtin_amdgcn_mfma_f32_16x16x32_f16(af, bf2, acc, 0,0,0);
    }
    #pragma unroll
    for (int r=0;r<4;++r) feat[g16*4+r][j] = (_Float16)fmaxf(acc[r]*sc2, 0.f);
  }
  __syncthreads();
  // Layer 3: K=256, N=176 (nout guard)
  for (int nt = wv; nt < 11; nt += 8){
    int j = nt*16 + l15;
    bool jv = (j < nout);
    const float* Bp = w3 + (size_t)j*256;
    v4f acc = {0.f,0.f,0.f,0.f};
    for (int kq = 0; kq < 8; ++kq){
      int k0 = kq*32 + 8*g16;
      v8h af = *reinterpret_cast<const v8h*>(&feat[l15][k0]);
      v8h bf2;
      #pragma unroll
      for (int e=0;e<8;++e){
        float wvv = jv ? Bp[k0+e] : 0.f;
        float q = rintf(wvv*inv3);
        q = fminf(fmaxf(q,-128.f),127.f);
        bf2[e] = (_Float16)q;
      }
      acc = __builtin_amdgcn_mfma_f32_16x16x32_f16(af, bf2, acc, 0,0,0);
    }
    #pragma unroll
    for (int r=0;r<4;++r) os[g16*4+r][j] = acc[r]*sc3;
  }
  __syncthreads();
  // Head: one wave per anchor
  for (int lm = wv; lm < 16; lm += 8){
    int m = m0 + lm;
    if (m >= cntA) continue;
    int a = offA + m;
    float s = anchors[2*a], e = anchors[2*a+1];
    // start-offset softmax
    float x0 = (lane < bb) ? os[lm][lane] : -1e30f;
    float x1 = (lane+64 < bb) ? os[lm][lane+64] : -1e30f;
    float mx = fmaxf(x0, x1);
    #pragma unroll
    for (int sh=1; sh<64; sh<<=1) mx = fmaxf(mx, __shfl_xor(mx, sh));
    float e0 = (lane < bb) ? expf(x0-mx) : 0.f;
    float e1 = (lane+64 < bb) ? expf(x1-mx) : 0.f;
    float se = e0 + e1;
    float ws2 = e0*((lane<bb)?sw[lane]:0.f) + e1*((lane+64<bb)?sw[lane+64]:0.f);
    #pragma unroll
    for (int sh=1; sh<64; sh<<=1){ se += __shfl_xor(se, sh); ws2 += __shfl_xor(ws2, sh); }
    float so = ws2/se;
    // end-offset softmax
    float y0 = (lane < bb) ? os[lm][bb+lane] : -1e30f;
    float y1 = (lane+64 < bb) ? os[lm][bb+lane+64] : -1e30f;
    float my = fmaxf(y0, y1);
    #pragma unroll
    for (int sh=1; sh<64; sh<<=1) my = fmaxf(my, __shfl_xor(my, sh));
    float f0 = (lane < bb) ? expf(y0-my) : 0.f;
    float f1 = (lane+64 < bb) ? expf(y1-my) : 0.f;
    float sf = f0 + f1;
    float wf = f0*((lane<bb)?ew[lane]:0.f) + f1*((lane+64<bb)?ew[lane+64]:0.f);
    #pragma unroll
    for (int sh=1; sh<64; sh<<=1){ sf += __shfl_xor(sf, sh); wf += __shfl_xor(wf, sh); }
    float eo = wf/sf;
    if (lane == 0){
      out[2*a]   = fminf(fmaxf(s+so, 0.f), al);
      out[2*a+1] = fminf(fmaxf(e+eo, 0.f), al);
      out[140+a] = os[lm][2*bb];
    }
    if (lane < 4) out[210+4*a+lane] = os[lm][2*bb+1+lane];
  }
}

extern "C" void kernel_launch(void* const* d_in, const int* in_sizes, int n_in,
                              void* d_out, int out_size, void* d_ws, size_t ws_size,
                              hipStream_t stream){
  const float* emb   = (const float*)d_in[0];
  const float* tpin  = (const float*)d_in[1];
  const float* npred = (const float*)d_in[2];
  const float* alen  = (const float*)d_in[3];
  const float* anch  = (const float*)d_in[4];
  const float* wih   = (const float*)d_in[5];
  const float* whh   = (const float*)d_in[6];
  const float* bih   = (const float*)d_in[7];
  const float* bhh   = (const float*)d_in[8];
  const float* w1    = (const float*)d_in[9];
  const float* w2    = (const float*)d_in[10];
  const float* w30   = (const float*)d_in[11];
  const float* w31   = (const float*)d_in[12];
  const float* w32   = (const float*)d_in[13];
  const float* sw0   = (const float*)d_in[14];
  const float* ew0   = (const float*)d_in[15];
  const float* sw1   = (const float*)d_in[16];
  const float* ew1   = (const float*)d_in[17];
  const float* sw2   = (const float*)d_in[18];
  const float* ew2   = (const float*)d_in[19];

  char* ws = (char*)d_ws;
  size_t off = 0;
  auto take = [&](size_t bytes)->char*{
    char* p = ws + off;
    off = (off + bytes + 255) & ~(size_t)255;
    return p;
  };
  float* abn    = (float*)take((size_t)NN*4);
  int*   order_ = (int*)  take((size_t)NA*MAXT*4);
  int*   cnteff = (int*)  take((size_t)NA*2*4);
  float* qs     = (float*)take(16*4);
  float* cm     = (float*)take((size_t)6*G3*4);
  uint4* whhB8  = (uint4*)take((size_t)6*8*64*24*16);
  _Float16* E   = (_Float16*)take((size_t)6*NNP*1024*2);
  float* hout   = (float*)take((size_t)NA*2*DD*4);
  (void)ws_size; (void)in_sizes; (void)n_in; (void)out_size;

  mega_kernel<<<dim3(4757), dim3(256), 0, stream>>>(npred, tpin, alen, anch, whh, wih, emb,
                                                    bih, bhh, w1, w2, w30, w31, w32,
                                                    abn, order_, cnteff, qs, cm, whhB8, E);
  gru_kernel<<<dim3(NA*2), dim3(512), 0, stream>>>(E, (const v4i*)whhB8, bhh, cm, order_, cnteff, hout);
  mlp_kernel<<<dim3(5), dim3(512), 0, stream>>>(hout, abn, anch, alen, w1, w2, w30, w31, w32, qs,
                                                sw0, ew0, sw1, ew1, sw2, ew2, (float*)d_out);
}

// Round 12
// 410.113 us; speedup vs baseline: 1.2397x; 1.0208x over previous
//
#include <hip/hip_runtime.h>
#include <math.h>

#define NN 1024
#define NNP 1025
#define DD 256
#define CC 5
#define G3 768
#define MAXT 512
#define NA 70

typedef _Float16 v8h __attribute__((ext_vector_type(8)));
typedef _Float16 v4h __attribute__((ext_vector_type(4)));
typedef float v4f __attribute__((ext_vector_type(4)));
typedef int v4i __attribute__((ext_vector_type(4)));

#define NF1 (3*16*17*64)
#define NF2 (3*16*8*64)
#define NF3 (3*11*8*64)

__device__ __forceinline__ float sigf(float x){ return __fdividef(1.f, 1.f + __expf(-x)); }
__device__ __forceinline__ float tanhf_fast(float x){ return 1.f - __fdividef(2.f, __expf(2.f*x) + 1.f); }

// ================= MEGA kernel =================
// [0,4)   abn ; [4,74) order ; [74,83) qs absmax ; [83,101) E bias row
// [101,125) whh colmax+int8 frags per (sd, w4)
// [125,4733) E-GEMM via MFMA fp16
__global__ __launch_bounds__(256) void mega_kernel(
    const float* __restrict__ node_pred, const float* __restrict__ tp_in,
    const float* __restrict__ audio_len, const float* __restrict__ anchors,
    const float* __restrict__ whh, const float* __restrict__ wih,
    const float* __restrict__ emb,
    const float* __restrict__ bih, const float* __restrict__ bhh,
    const float* __restrict__ w1, const float* __restrict__ w2,
    const float* __restrict__ w30, const float* __restrict__ w31, const float* __restrict__ w32,
    float* __restrict__ abn, int* __restrict__ order, int* __restrict__ cnteff,
    float* __restrict__ qs, float* __restrict__ cm,
    uint4* __restrict__ whhB8, _Float16* __restrict__ E){
  __shared__ __align__(16) unsigned char smem[16*264*2];
  int b = blockIdx.x, tid = threadIdx.x;
  if (b < 4){
    int i = b*256 + tid;
    float pv[CC]; float m = -1e30f;
    for (int c=0;c<CC;++c){ pv[c]=node_pred[i*CC+c]; m=fmaxf(m,pv[c]); }
    float s=0.f;
    for (int c=0;c<CC;++c) s += expf(pv[c]-m);
    abn[i] = expf(pv[0]-m)/s;
  } else if (b < 74){
    if (tid >= 64) return;
    int a = b-4; int lane = tid;
    float al = audio_len[0];
    float s = anchors[2*a], e = anchors[2*a+1];
    int* ord = order + a*MAXT;
    int cnt = 0;
    for (int base=0; base<NN; base+=64){
      float tp = tp_in[base+lane]*al;
      bool msk = (tp>=s)&&(tp<=e);
      unsigned long long bal = __ballot(msk);
      int off = (int)__popcll(bal & ((1ull<<lane)-1ull));
      if (msk && (cnt+off)<MAXT) ord[cnt+off] = base+lane;
      cnt += (int)__popcll(bal);
    }
    if (lane==0){ int c = cnt<MAXT?cnt:MAXT; cnteff[2*a]=c; cnteff[2*a+1]=(c>0)?c:1; }
  } else if (b < 83){
    int m = b-74;
    const float* p; int n;
    if (m<3){ p = w1 + (size_t)m*256*519; n = 256*519; }
    else if (m<6){ p = w2 + (size_t)(m-3)*256*256; n = 256*256; }
    else { p = (m==6)?w30:((m==7)?w31:w32); n = ((m==7)?125:165)*256; }
    float mx = 0.f;
    for (int i=tid;i<n;i+=256) mx = fmaxf(mx, fabsf(p[i]));
    float* red = (float*)smem;
    red[tid]=mx; __syncthreads();
    for (int sft=128; sft>0; sft>>=1){ if (tid<sft) red[tid]=fmaxf(red[tid],red[tid+sft]); __syncthreads(); }
    if (tid==0) qs[m] = fmaxf(red[0]/127.f, 1e-8f);
  } else if (b < 101){
    int i = (b-83)*256 + tid;
    if (i >= 4608) return;
    int gt = i % 3; int c = (i/3)&255; int sd = i/768;
    int j = gt*256 + c;
    float v = bih[sd*G3+j] + ((gt<2)? bhh[sd*G3+j] : 0.f);
    E[((size_t)(sd*NNP + NN))*1024 + c*4 + gt] = (_Float16)v;
  } else if (b < 125){
    // whh colmax + int8 fragment pack per (sd, w), 4-wave gru layout (12 n-tiles)
    int bb = b-101;
    int sd = bb>>2, w = bb&3;
    float* cm_lds = (float*)smem;         // 192 floats
    int lane = tid & 63, wv = tid >> 6;
    for (int it=0; it<48; ++it){
      int lr = it*4 + wv;                 // 0..191
      int gt = lr>>6, cc = lr&63;
      int j = gt*256 + w*64 + cc;
      float4 v = reinterpret_cast<const float4*>(whh + ((size_t)sd*G3 + j)*DD)[lane];
      float mx = fmaxf(fmaxf(fabsf(v.x),fabsf(v.y)), fmaxf(fabsf(v.z),fabsf(v.w)));
      #pragma unroll
      for (int sh=1; sh<64; sh<<=1) mx = fmaxf(mx, __shfl_xor(mx, sh));
      if (lane==0){
        float cmax = fmaxf(mx, 1e-12f);
        cm_lds[lr] = cmax;
        cm[sd*G3 + j] = cmax;
      }
    }
    __syncthreads();
    #pragma unroll
    for (int ee=0; ee<12; ++ee){
      int il = tid*12 + ee;               // 0..3071 = lane2*48 + nt*4 + q
      int lane2 = il/48; int rr = il - lane2*48;
      int nt = rr>>2; int q = rr&3;
      int gt = nt>>2, s = nt&3;
      int j  = gt*256 + w*64 + s*16 + (lane2&15);
      int lr = gt*64  + s*16 + (lane2&15);
      int kbase = 64*q + 16*(lane2>>4);
      float inv = 127.f/cm_lds[lr];
      const float* src = whh + ((size_t)sd*G3 + j)*DD + kbase;
      unsigned int dw[4];
      #pragma unroll
      for (int d2=0; d2<4; ++d2){
        unsigned int acc = 0;
        #pragma unroll
        for (int e2=0; e2<4; ++e2){
          float qv = rintf(src[4*d2+e2]*inv);
          qv = fminf(fmaxf(qv,-127.f),127.f);
          int iq = (int)qv;
          acc |= ((unsigned int)(iq & 255)) << (8*e2);
        }
        dw[d2] = acc;
      }
      uint4 v; v.x=dw[0]; v.y=dw[1]; v.z=dw[2]; v.w=dw[3];
      whhB8[(size_t)(sd*4 + w)*3072 + il] = v;
    }
  } else {
    // E-GEMM: 16-row tile x 4 col-tiles (4 waves); A staged LDS fp16
    typedef _Float16 AsT[264];
    AsT* As = (AsT*)smem;
    int b2 = b - 125;
    int sd = b2 / 768;
    int rem = b2 - sd*768;
    int r_t = rem & 63, cg = rem >> 6;
    int row0 = r_t*16;
    int lane = tid & 63, wv = tid >> 6;
    int l15 = lane & 15, g16 = lane >> 4;
    {
      int rr = tid>>4, k0 = (tid&15)*16;
      const float4* ep = reinterpret_cast<const float4*>(emb + (size_t)(row0+rr)*DD + k0);
      #pragma unroll
      for (int f=0; f<4; ++f){
        float4 v = ep[f];
        v4h o; o[0]=(_Float16)v.x; o[1]=(_Float16)v.y; o[2]=(_Float16)v.z; o[3]=(_Float16)v.w;
        *reinterpret_cast<v4h*>(&As[rr][k0 + f*4]) = o;
      }
    }
    __syncthreads();
    int c_t = cg*4 + wv;
    int j = c_t*16 + l15;
    const float* Bp = wih + ((size_t)sd*G3 + j)*DD + 8*g16;
    float bsum = bih[sd*G3 + j] + (((j>>8) < 2) ? bhh[sd*G3 + j] : 0.f);
    v4f acc = {0.f,0.f,0.f,0.f};
    #pragma unroll
    for (int q=0;q<8;++q){
      v8h af = *reinterpret_cast<const v8h*>(&As[l15][32*q + 8*g16]);
      float4 b0 = *reinterpret_cast<const float4*>(Bp + 32*q);
      float4 b1 = *reinterpret_cast<const float4*>(Bp + 32*q + 4);
      v8h bf;
      bf[0]=(_Float16)b0.x; bf[1]=(_Float16)b0.y; bf[2]=(_Float16)b0.z; bf[3]=(_Float16)b0.w;
      bf[4]=(_Float16)b1.x; bf[5]=(_Float16)b1.y; bf[6]=(_Float16)b1.z; bf[7]=(_Float16)b1.w;
      acc = __builtin_amdgcn_mfma_f32_16x16x32_f16(af, bf, acc, 0,0,0);
    }
    int gt = j>>8, c = j&255;
    #pragma unroll
    for (int r=0;r<4;++r){
      int row = row0 + g16*4 + r;
      E[((size_t)(sd*NNP + row))*1024 + c*4 + gt] = (_Float16)(acc[r] + bsum);
    }
  }
}

// ================= GRU launch: blocks [0,140) GRU (4 waves) ; blocks >=140 MLP frag pack =================
__global__ __launch_bounds__(256, 1) void gru_kernel(
    const _Float16* __restrict__ E, const v4i* __restrict__ whhB8,
    const float* __restrict__ bhh, const float* __restrict__ cm,
    const int* __restrict__ order, const int* __restrict__ cnteff,
    float* __restrict__ hout,
    const float* __restrict__ w1, const float* __restrict__ w2,
    const float* __restrict__ w30, const float* __restrict__ w31, const float* __restrict__ w32,
    const float* __restrict__ qs,
    v8h* __restrict__ w1F, v8h* __restrict__ w2F, v8h* __restrict__ w3F){
  int blk = blockIdx.x;
  int tid = threadIdx.x;
  if (blk >= NA*2){
    // ---- MLP weight fragment packing (quantized-integer fp16, lane-major coalesced) ----
    int i = (blk - NA*2)*256 + tid;
    if (i < NF1){
      int lane = i & 63; int rest = i >> 6;
      int q = rest % 17; int rc = rest / 17;
      int ct = rc & 15; int si = rc >> 4;
      int j = ct*16 + (lane&15);
      int k0 = q*32 + 8*(lane>>4);
      float inv = 1.f/qs[si];
      const float* src = w1 + ((size_t)(si*256 + j))*519;
      v8h o;
      #pragma unroll
      for (int e=0;e<8;++e){
        int k = k0+e;
        float wv = (k<519)? src[k] : 0.f;
        float qv = rintf(wv*inv);
        qv = fminf(fmaxf(qv,-128.f),127.f);
        o[e] = (_Float16)qv;
      }
      w1F[i] = o;
    } else if (i < NF1+NF2){
      int r = i - NF1;
      int lane = r & 63; int rest = r >> 6;
      int q = rest & 7; int rc = rest >> 3;
      int ct = rc & 15; int si = rc >> 4;
      int j = ct*16 + (lane&15);
      int k0 = q*32 + 8*(lane>>4);
      float inv = 1.f/qs[3+si];
      const float* src = w2 + ((size_t)(si*256 + j))*256 + k0;
      v8h o;
      #pragma unroll
      for (int e=0;e<8;++e){
        float qv = rintf(src[e]*inv);
        qv = fminf(fmaxf(qv,-128.f),127.f);
        o[e] = (_Float16)qv;
      }
      w2F[r] = o;
    } else if (i < NF1+NF2+NF3){
      int r = i - NF1 - NF2;
      int lane = r & 63; int rest = r >> 6;
      int q = rest & 7; int rc = rest >> 3;
      int ct = rc % 11; int si = rc / 11;
      int j = ct*16 + (lane&15);
      int nout = (si==1)?125:165;
      const float* w3 = (si==0)?w30:((si==1)?w31:w32);
      int k0 = q*32 + 8*(lane>>4);
      float inv = 1.f/qs[6+si];
      v8h o;
      #pragma unroll
      for (int e=0;e<8;++e){
        float wv = (j<nout)? w3[(size_t)j*256 + k0+e] : 0.f;
        float qv = rintf(wv*inv);
        qv = fminf(fmaxf(qv,-128.f),127.f);
        o[e] = (_Float16)qv;
      }
      w3F[r] = o;
    }
    return;
  }
  // ---- GRU proper: 4 waves, wave w owns cells [w*64, w*64+64) as 12 n-tiles ----
  int a = blk>>1, d = blk&1;
  int si = (a<15)?0:((a<55)?1:2);
  int sd = si*2+d;
  int w = tid>>6, lane = tid&63;
  int g16 = lane>>4, l15 = lane&15;

  __shared__ int ord_s[MAXT];
  __shared__ alignas(16) signed char h8[2][DD];

  ord_s[tid]     = order[a*MAXT + tid];
  ord_s[tid+256] = order[a*MAXT + tid + 256];
  h8[0][tid] = 0;

  int cnt = cnteff[2*a], eff = cnteff[2*a+1];

  int c = w*64 + g16*16 + l15;              // this lane's cell (all 256 distinct)
  float bn = bhh[sd*G3 + 2*DD + c];
  const float ISQ = 1.f/(127.f*127.f);
  float sr = cm[sd*G3 +       c]*ISQ;
  float sz = cm[sd*G3 + 256 + c]*ISQ;
  float sn = cm[sd*G3 + 512 + c]*ISQ;

  // B fragments: 48 x v4i = 192 dwords resident
  v4i bf[12][4];
  {
    const v4i* wp = whhB8 + (((size_t)sd*4 + w)*64 + lane)*48;
    #pragma unroll
    for (int nt=0;nt<12;++nt)
      #pragma unroll
      for (int q=0;q<4;++q)
        bf[nt][q] = wp[nt*4+q];
  }

  const uint2* Eb = reinterpret_cast<const uint2*>(E) + (size_t)sd*NNP*256;

  // RACE FIX (round-11 crash): barrier BEFORE any read of ord_s — the writer of
  // ord_s[idx0] is usually a different wave; pre-barrier reads saw stale LDS and
  // produced a wild E address.
  __syncthreads();

  float h = 0.f;
  uint2 gEven, gOdd;
  {
    int idx0 = d ? (eff-1) : 0;
    int n0 = (idx0 < cnt) ? ord_s[idx0] : NN;
    gEven = Eb[(size_t)n0*256 + c];
  }

  for (int t=0;t<eff;++t){
    int p = t & 1;
    if (t+1 < eff){
      int idx1 = d ? (eff-2-t) : (t+1);
      int n1 = (idx1 < cnt) ? ord_s[idx1] : NN;
      if (p==0) gOdd  = Eb[(size_t)n1*256 + c];
      else      gEven = Eb[(size_t)n1*256 + c];
    }
    v4i a0={0,0,0,0}, a1={0,0,0,0}, a2={0,0,0,0}, a3={0,0,0,0};
    v4i a4={0,0,0,0}, a5={0,0,0,0}, a6={0,0,0,0}, a7={0,0,0,0};
    v4i a8={0,0,0,0}, a9={0,0,0,0}, a10={0,0,0,0}, a11={0,0,0,0};
    #pragma unroll
    for (int q=0;q<4;++q){
      v4i af = *reinterpret_cast<const v4i*>(&h8[p][64*q + 16*g16]);
      a0  = __builtin_amdgcn_mfma_i32_16x16x64_i8(af, bf[0][q],  a0,  0,0,0);
      a1  = __builtin_amdgcn_mfma_i32_16x16x64_i8(af, bf[1][q],  a1,  0,0,0);
      a2  = __builtin_amdgcn_mfma_i32_16x16x64_i8(af, bf[2][q],  a2,  0,0,0);
      a3  = __builtin_amdgcn_mfma_i32_16x16x64_i8(af, bf[3][q],  a3,  0,0,0);
      a4  = __builtin_amdgcn_mfma_i32_16x16x64_i8(af, bf[4][q],  a4,  0,0,0);
      a5  = __builtin_amdgcn_mfma_i32_16x16x64_i8(af, bf[5][q],  a5,  0,0,0);
      a6  = __builtin_amdgcn_mfma_i32_16x16x64_i8(af, bf[6][q],  a6,  0,0,0);
      a7  = __builtin_amdgcn_mfma_i32_16x16x64_i8(af, bf[7][q],  a7,  0,0,0);
      a8  = __builtin_amdgcn_mfma_i32_16x16x64_i8(af, bf[8][q],  a8,  0,0,0);
      a9  = __builtin_amdgcn_mfma_i32_16x16x64_i8(af, bf[9][q],  a9,  0,0,0);
      a10 = __builtin_amdgcn_mfma_i32_16x16x64_i8(af, bf[10][q], a10, 0,0,0);
      a11 = __builtin_amdgcn_mfma_i32_16x16x64_i8(af, bf[11][q], a11, 0,0,0);
    }
    v4h ev = __builtin_bit_cast(v4h, (p==0) ? gEven : gOdd);
    int ir  = (g16==0)?a0[0]:((g16==1)?a1[0]:((g16==2)?a2[0]:a3[0]));
    int iz  = (g16==0)?a4[0]:((g16==1)?a5[0]:((g16==2)?a6[0]:a7[0]));
    int inn = (g16==0)?a8[0]:((g16==1)?a9[0]:((g16==2)?a10[0]:a11[0]));
    float r  = sigf((float)ev[0] + (float)ir*sr);
    float z  = sigf((float)ev[1] + (float)iz*sz);
    float nv = tanhf_fast((float)ev[2] + r*((float)inn*sn + bn));
    h = z*(h - nv) + nv;
    h8[p^1][c] = (signed char)(int)rintf(h*127.f);
    __syncthreads();
  }
  hout[(size_t)(2*a+d)*DD + c] = h;
}

// ================= MLP via MFMA fp16, pre-packed quantized fragments =================
__global__ __launch_bounds__(512) void mlp_kernel(
    const float* __restrict__ hout, const float* __restrict__ abn,
    const float* __restrict__ anchors, const float* __restrict__ audio_len,
    const v8h* __restrict__ w1F, const v8h* __restrict__ w2F, const v8h* __restrict__ w3F,
    const float* __restrict__ qs,
    const float* __restrict__ sw0, const float* __restrict__ ew0,
    const float* __restrict__ sw1, const float* __restrict__ ew1,
    const float* __restrict__ sw2, const float* __restrict__ ew2,
    float* __restrict__ out){
  int bm = blockIdx.x;
  int si = (bm==0)?0:((bm<4)?1:2);
  int mt = (bm==0)?0:((bm<4)?(bm-1):0);
  int cntA = (si==1)?40:15;
  int offA = (si==0)?0:((si==1)?15:55);
  int bb   = (si==1)?60:80;
  int m0 = mt*16;
  const float* sw = (si==0)?sw0:((si==1)?sw1:sw2);
  const float* ew = (si==0)?ew0:((si==1)?ew1:ew2);
  float al = audio_len[0];

  __shared__ _Float16 feat[16][552];
  __shared__ _Float16 h1s[16][264];
  __shared__ float    os[16][184];

  int tid = threadIdx.x;
  int lane = tid & 63, wv = tid >> 6;
  int l15 = lane & 15, g16 = lane >> 4;

  for (int idx = tid; idx < 16*552; idx += 512){
    int r = idx / 552, c2 = idx - r*552;
    float v = 0.f;
    int m = m0 + r;
    if (m < cntA){
      int a = offA + m;
      if (c2 < 256)       v = hout[(size_t)(2*a)*DD + c2];
      else if (c2 < 512)  v = hout[(size_t)(2*a+1)*DD + (c2-256)];
      else if (c2 == 512) v = abn[m];
      else if (c2 == 513){ float s=anchors[2*a], e=anchors[2*a+1]; v = (s+e)*0.5f/al; }
      else if (c2 == 514){ float s=anchors[2*a], e=anchors[2*a+1]; v = (e-s)/al; }
    }
    feat[r][c2] = (_Float16)v;
  }
  __syncthreads();
  float sc1 = qs[si], sc2 = qs[3+si], sc3 = qs[6+si];

  // Layer 1: K=544 (17 kq), N=256
  for (int nt = wv; nt < 16; nt += 8){
    int j = nt*16 + l15;
    const v8h* bp = w1F + (size_t)(si*16 + nt)*17*64 + lane;
    v4f acc = {0.f,0.f,0.f,0.f};
    for (int kq = 0; kq < 17; ++kq){
      v8h af = *reinterpret_cast<const v8h*>(&feat[l15][kq*32 + 8*g16]);
      acc = __builtin_amdgcn_mfma_f32_16x16x32_f16(af, bp[kq*64], acc, 0,0,0);
    }
    #pragma unroll
    for (int r=0;r<4;++r) h1s[g16*4+r][j] = (_Float16)fmaxf(acc[r]*sc1, 0.f);
  }
  __syncthreads();
  // Layer 2: K=256, N=256
  for (int nt = wv; nt < 16; nt += 8){
    int j = nt*16 + l15;
    const v8h* bp = w2F + (size_t)(si*16 + nt)*8*64 + lane;
    v4f acc = {0.f,0.f,0.f,0.f};
    for (int kq = 0; kq < 8; ++kq){
      v8h af = *reinterpret_cast<const v8h*>(&h1s[l15][kq*32 + 8*g16]);
      acc = __builtin_amdgcn_mfma_f32_16x16x32_f16(af, bp[kq*64], acc, 0,0,0);
    }
    #pragma unroll
    for (int r=0;r<4;++r) feat[g16*4+r][j] = (_Float16)fmaxf(acc[r]*sc2, 0.f);
  }
  __syncthreads();
  // Layer 3: K=256, N=176
  for (int nt = wv; nt < 11; nt += 8){
    int j = nt*16 + l15;
    const v8h* bp = w3F + (size_t)(si*11 + nt)*8*64 + lane;
    v4f acc = {0.f,0.f,0.f,0.f};
    for (int kq = 0; kq < 8; ++kq){
      v8h af = *reinterpret_cast<const v8h*>(&feat[l15][kq*32 + 8*g16]);
      acc = __builtin_amdgcn_mfma_f32_16x16x32_f16(af, bp[kq*64], acc, 0,0,0);
    }
    #pragma unroll
    for (int r=0;r<4;++r) os[g16*4+r][j] = acc[r]*sc3;
  }
  __syncthreads();
  // Head: one wave per anchor
  for (int lm = wv; lm < 16; lm += 8){
    int m = m0 + lm;
    if (m >= cntA) continue;
    int a = offA + m;
    float s = anchors[2*a], e = anchors[2*a+1];
    float x0 = (lane < bb) ? os[lm][lane] : -1e30f;
    float x1 = (lane+64 < bb) ? os[lm][lane+64] : -1e30f;
    float mx = fmaxf(x0, x1);
    #pragma unroll
    for (int sh=1; sh<64; sh<<=1) mx = fmaxf(mx, __shfl_xor(mx, sh));
    float e0 = (lane < bb) ? expf(x0-mx) : 0.f;
    float e1 = (lane+64 < bb) ? expf(x1-mx) : 0.f;
    float se = e0 + e1;
    float ws2 = e0*((lane<bb)?sw[lane]:0.f) + e1*((lane+64<bb)?sw[lane+64]:0.f);
    #pragma unroll
    for (int sh=1; sh<64; sh<<=1){ se += __shfl_xor(se, sh); ws2 += __shfl_xor(ws2, sh); }
    float so = ws2/se;
    float y0 = (lane < bb) ? os[lm][bb+lane] : -1e30f;
    float y1 = (lane+64 < bb) ? os[lm][bb+lane+64] : -1e30f;
    float my = fmaxf(y0, y1);
    #pragma unroll
    for (int sh=1; sh<64; sh<<=1) my = fmaxf(my, __shfl_xor(my, sh));
    float f0 = (lane < bb) ? expf(y0-my) : 0.f;
    float f1 = (lane+64 < bb) ? expf(y1-my) : 0.f;
    float sf = f0 + f1;
    float wf = f0*((lane<bb)?ew[lane]:0.f) + f1*((lane+64<bb)?ew[lane+64]:0.f);
    #pragma unroll
    for (int sh=1; sh<64; sh<<=1){ sf += __shfl_xor(sf, sh); wf += __shfl_xor(wf, sh); }
    float eo = wf/sf;
    if (lane == 0){
      out[2*a]   = fminf(fmaxf(s+so, 0.f), al);
      out[2*a+1] = fminf(fmaxf(e+eo, 0.f), al);
      out[140+a] = os[lm][2*bb];
    }
    if (lane < 4) out[210+4*a+lane] = os[lm][2*bb+1+lane];
  }
}

extern "C" void kernel_launch(void* const* d_in, const int* in_sizes, int n_in,
                              void* d_out, int out_size, void* d_ws, size_t ws_size,
                              hipStream_t stream){
  const float* emb   = (const float*)d_in[0];
  const float* tpin  = (const float*)d_in[1];
  const float* npred = (const float*)d_in[2];
  const float* alen  = (const float*)d_in[3];
  const float* anch  = (const float*)d_in[4];
  const float* wih   = (const float*)d_in[5];
  const float* whh   = (const float*)d_in[6];
  const float* bih   = (const float*)d_in[7];
  const float* bhh   = (const float*)d_in[8];
  const float* w1    = (const float*)d_in[9];
  const float* w2    = (const float*)d_in[10];
  const float* w30   = (const float*)d_in[11];
  const float* w31   = (const float*)d_in[12];
  const float* w32   = (const float*)d_in[13];
  const float* sw0   = (const float*)d_in[14];
  const float* ew0   = (const float*)d_in[15];
  const float* sw1   = (const float*)d_in[16];
  const float* ew1   = (const float*)d_in[17];
  const float* sw2   = (const float*)d_in[18];
  const float* ew2   = (const float*)d_in[19];

  char* ws = (char*)d_ws;
  size_t off = 0;
  auto take = [&](size_t bytes)->char*{
    char* p = ws + off;
    off = (off + bytes + 255) & ~(size_t)255;
    return p;
  };
  float* abn    = (float*)take((size_t)NN*4);
  int*   order_ = (int*)  take((size_t)NA*MAXT*4);
  int*   cnteff = (int*)  take((size_t)NA*2*4);
  float* qs     = (float*)take(16*4);
  float* cm     = (float*)take((size_t)6*G3*4);
  uint4* whhB8  = (uint4*)take((size_t)6*4*3072*16);
  _Float16* E   = (_Float16*)take((size_t)6*NNP*1024*2);
  float* hout   = (float*)take((size_t)NA*2*DD*4);
  v8h* w1F      = (v8h*)take((size_t)NF1*16);
  v8h* w2F      = (v8h*)take((size_t)NF2*16);
  v8h* w3F      = (v8h*)take((size_t)NF3*16);
  (void)ws_size; (void)in_sizes; (void)n_in; (void)out_size;

  mega_kernel<<<dim3(4733), dim3(256), 0, stream>>>(npred, tpin, alen, anch, whh, wih, emb,
                                                    bih, bhh, w1, w2, w30, w31, w32,
                                                    abn, order_, cnteff, qs, cm, whhB8, E);
  {
    const int packBlocks = (NF1+NF2+NF3+255)/256;   // 366
    gru_kernel<<<dim3(NA*2 + packBlocks), dim3(256), 0, stream>>>(
        E, (const v4i*)whhB8, bhh, cm, order_, cnteff, hout,
        w1, w2, w30, w31, w32, qs, w1F, w2F, w3F);
  }
  mlp_kernel<<<dim3(5), dim3(512), 0, stream>>>(hout, abn, anch, alen, w1F, w2F, w3F, qs,
                                                sw0, ew0, sw1, ew1, sw2, ew2, (float*)d_out);
}

// Round 13
// 388.992 us; speedup vs baseline: 1.3070x; 1.0543x over previous
//
#include <hip/hip_runtime.h>
#include <math.h>

#define NN 1024
#define NNP 1025
#define DD 256
#define CC 5
#define G3 768
#define MAXT 512
#define NA 70

typedef _Float16 v8h __attribute__((ext_vector_type(8)));
typedef _Float16 v4h __attribute__((ext_vector_type(4)));
typedef float v4f __attribute__((ext_vector_type(4)));
typedef int v4i __attribute__((ext_vector_type(4)));

#define NF1 (3*16*17*64)
#define NF2 (3*16*8*64)
#define NF3 (3*11*8*64)
#define NFT (NF1+NF2+NF3)

__device__ __forceinline__ float sigf(float x){ return __fdividef(1.f, 1.f + __expf(-x)); }
__device__ __forceinline__ float tanhf_fast(float x){ return 1.f - __fdividef(2.f, __expf(2.f*x) + 1.f); }

// ================= MEGA kernel (round-10 layout) =================
// [0,4) abn ; [4,74) order ; [74,83) qs absmax ; [83,101) E bias row
// [101,149) whh colmax + int8 frags per (sd, w8)  [8-wave gru layout]
// [149,4757) E-GEMM via MFMA fp16
__global__ __launch_bounds__(256) void mega_kernel(
    const float* __restrict__ node_pred, const float* __restrict__ tp_in,
    const float* __restrict__ audio_len, const float* __restrict__ anchors,
    const float* __restrict__ whh, const float* __restrict__ wih,
    const float* __restrict__ emb,
    const float* __restrict__ bih, const float* __restrict__ bhh,
    const float* __restrict__ w1, const float* __restrict__ w2,
    const float* __restrict__ w30, const float* __restrict__ w31, const float* __restrict__ w32,
    float* __restrict__ abn, int* __restrict__ order, int* __restrict__ cnteff,
    float* __restrict__ qs, float* __restrict__ cm,
    uint4* __restrict__ whhB8, _Float16* __restrict__ E){
  __shared__ __align__(16) unsigned char smem[16*264*2];
  int b = blockIdx.x, tid = threadIdx.x;
  if (b < 4){
    int i = b*256 + tid;
    float pv[CC]; float m = -1e30f;
    for (int c=0;c<CC;++c){ pv[c]=node_pred[i*CC+c]; m=fmaxf(m,pv[c]); }
    float s=0.f;
    for (int c=0;c<CC;++c) s += expf(pv[c]-m);
    abn[i] = expf(pv[0]-m)/s;
  } else if (b < 74){
    if (tid >= 64) return;
    int a = b-4; int lane = tid;
    float al = audio_len[0];
    float s = anchors[2*a], e = anchors[2*a+1];
    int* ord = order + a*MAXT;
    int cnt = 0;
    for (int base=0; base<NN; base+=64){
      float tp = tp_in[base+lane]*al;
      bool msk = (tp>=s)&&(tp<=e);
      unsigned long long bal = __ballot(msk);
      int off = (int)__popcll(bal & ((1ull<<lane)-1ull));
      if (msk && (cnt+off)<MAXT) ord[cnt+off] = base+lane;
      cnt += (int)__popcll(bal);
    }
    if (lane==0){ int c = cnt<MAXT?cnt:MAXT; cnteff[2*a]=c; cnteff[2*a+1]=(c>0)?c:1; }
  } else if (b < 83){
    int m = b-74;
    const float* p; int n;
    if (m<3){ p = w1 + (size_t)m*256*519; n = 256*519; }
    else if (m<6){ p = w2 + (size_t)(m-3)*256*256; n = 256*256; }
    else { p = (m==6)?w30:((m==7)?w31:w32); n = ((m==7)?125:165)*256; }
    float mx = 0.f;
    for (int i=tid;i<n;i+=256) mx = fmaxf(mx, fabsf(p[i]));
    float* red = (float*)smem;
    red[tid]=mx; __syncthreads();
    for (int sft=128; sft>0; sft>>=1){ if (tid<sft) red[tid]=fmaxf(red[tid],red[tid+sft]); __syncthreads(); }
    if (tid==0) qs[m] = fmaxf(red[0]/127.f, 1e-8f);
  } else if (b < 101){
    int i = (b-83)*256 + tid;
    if (i >= 4608) return;
    int gt = i % 3; int c = (i/3)&255; int sd = i/768;
    int j = gt*256 + c;
    float v = bih[sd*G3+j] + ((gt<2)? bhh[sd*G3+j] : 0.f);
    E[((size_t)(sd*NNP + NN))*1024 + c*4 + gt] = (_Float16)v;
  } else if (b < 149){
    // whh colmax + int8 fragment pack per (sd, w), 8-wave gru layout (6 n-tiles)
    int bb = b-101;
    int sd = bb>>3, w = bb&7;
    float* cm_lds = (float*)smem;         // 96 floats
    int lane = tid & 63, wv = tid >> 6;
    for (int it=0; it<24; ++it){
      int lr = it*4 + wv;                 // 0..95
      int gt = lr>>5, c = lr&31;
      int j = gt*256 + w*32 + c;
      float4 v = reinterpret_cast<const float4*>(whh + ((size_t)sd*G3 + j)*DD)[lane];
      float mx = fmaxf(fmaxf(fabsf(v.x),fabsf(v.y)), fmaxf(fabsf(v.z),fabsf(v.w)));
      #pragma unroll
      for (int sh=1; sh<64; sh<<=1) mx = fmaxf(mx, __shfl_xor(mx, sh));
      if (lane==0){
        float cmax = fmaxf(mx, 1e-12f);
        cm_lds[lr] = cmax;
        cm[sd*G3 + j] = cmax;
      }
    }
    __syncthreads();
    #pragma unroll
    for (int ee=0; ee<6; ++ee){
      int il = tid*6 + ee;                // 0..1535 = lane2*24 + nt*4 + q
      int q    = il & 3;
      int nt   = (il>>2) % 6;
      int lane2= il / 24;
      int gt = nt>>1, half = nt&1;
      int j  = gt*256 + w*32 + half*16 + (lane2&15);
      int lr = gt*32  + half*16 + (lane2&15);
      int kbase = 64*q + 16*(lane2>>4);
      float inv = 127.f/cm_lds[lr];
      const float* src = whh + ((size_t)sd*G3 + j)*DD + kbase;
      unsigned int dw[4];
      #pragma unroll
      for (int d2=0; d2<4; ++d2){
        unsigned int acc = 0;
        #pragma unroll
        for (int e2=0; e2<4; ++e2){
          float qv = rintf(src[4*d2+e2]*inv);
          qv = fminf(fmaxf(qv,-127.f),127.f);
          int iq = (int)qv;
          acc |= ((unsigned int)(iq & 255)) << (8*e2);
        }
        dw[d2] = acc;
      }
      uint4 v; v.x=dw[0]; v.y=dw[1]; v.z=dw[2]; v.w=dw[3];
      whhB8[(size_t)(sd*8 + w)*1536 + il] = v;
    }
  } else {
    // E-GEMM: 16-row tile x 4 col-tiles (4 waves); A staged LDS fp16
    typedef _Float16 AsT[264];
    AsT* As = (AsT*)smem;
    int b2 = b - 149;
    int sd = b2 / 768;
    int rem = b2 - sd*768;
    int r_t = rem & 63, cg = rem >> 6;
    int row0 = r_t*16;
    int lane = tid & 63, wv = tid >> 6;
    int l15 = lane & 15, g16 = lane >> 4;
    {
      int rr = tid>>4, k0 = (tid&15)*16;
      const float4* ep = reinterpret_cast<const float4*>(emb + (size_t)(row0+rr)*DD + k0);
      #pragma unroll
      for (int f=0; f<4; ++f){
        float4 v = ep[f];
        v4h o; o[0]=(_Float16)v.x; o[1]=(_Float16)v.y; o[2]=(_Float16)v.z; o[3]=(_Float16)v.w;
        *reinterpret_cast<v4h*>(&As[rr][k0 + f*4]) = o;
      }
    }
    __syncthreads();
    int c_t = cg*4 + wv;
    int j = c_t*16 + l15;
    const float* Bp = wih + ((size_t)sd*G3 + j)*DD + 8*g16;
    float bsum = bih[sd*G3 + j] + (((j>>8) < 2) ? bhh[sd*G3 + j] : 0.f);
    v4f acc = {0.f,0.f,0.f,0.f};
    #pragma unroll
    for (int q=0;q<8;++q){
      v8h af = *reinterpret_cast<const v8h*>(&As[l15][32*q + 8*g16]);
      float4 b0 = *reinterpret_cast<const float4*>(Bp + 32*q);
      float4 b1 = *reinterpret_cast<const float4*>(Bp + 32*q + 4);
      v8h bf;
      bf[0]=(_Float16)b0.x; bf[1]=(_Float16)b0.y; bf[2]=(_Float16)b0.z; bf[3]=(_Float16)b0.w;
      bf[4]=(_Float16)b1.x; bf[5]=(_Float16)b1.y; bf[6]=(_Float16)b1.z; bf[7]=(_Float16)b1.w;
      acc = __builtin_amdgcn_mfma_f32_16x16x32_f16(af, bf, acc, 0,0,0);
    }
    int gt = j>>8, c = j&255;
    #pragma unroll
    for (int r=0;r<4;++r){
      int row = row0 + g16*4 + r;
      E[((size_t)(sd*NNP + row))*1024 + c*4 + gt] = (_Float16)(acc[r] + bsum);
    }
  }
}

// ================= GRU launch: blocks [0,140) GRU (8 waves, round-8 structure) ; blocks >=140 MLP frag pack =================
__global__ __launch_bounds__(512, 2) void gru_kernel(
    const _Float16* __restrict__ E, const v4i* __restrict__ whhB8,
    const float* __restrict__ bhh, const float* __restrict__ cm,
    const int* __restrict__ order, const int* __restrict__ cnteff,
    float* __restrict__ hout,
    const float* __restrict__ w1, const float* __restrict__ w2,
    const float* __restrict__ w30, const float* __restrict__ w31, const float* __restrict__ w32,
    const float* __restrict__ qs,
    v8h* __restrict__ w1F, v8h* __restrict__ w2F, v8h* __restrict__ w3F){
  int blk = blockIdx.x;
  int tid = threadIdx.x;
  if (blk >= NA*2){
    // ---- MLP weight fragment packing (quantized-integer fp16, lane-major coalesced) ----
    int i = (blk - NA*2)*512 + tid;
    if (i < NF1){
      int lane = i & 63; int rest = i >> 6;
      int q = rest % 17; int rc = rest / 17;
      int ct = rc & 15; int si = rc >> 4;
      int j = ct*16 + (lane&15);
      int k0 = q*32 + 8*(lane>>4);
      float inv = 1.f/qs[si];
      const float* src = w1 + ((size_t)(si*256 + j))*519;
      v8h o;
      #pragma unroll
      for (int e=0;e<8;++e){
        int k = k0+e;
        float wv = (k<519)? src[k] : 0.f;
        float qv = rintf(wv*inv);
        qv = fminf(fmaxf(qv,-128.f),127.f);
        o[e] = (_Float16)qv;
      }
      w1F[i] = o;
    } else if (i < NF1+NF2){
      int r = i - NF1;
      int lane = r & 63; int rest = r >> 6;
      int q = rest & 7; int rc = rest >> 3;
      int ct = rc & 15; int si = rc >> 4;
      int j = ct*16 + (lane&15);
      int k0 = q*32 + 8*(lane>>4);
      float inv = 1.f/qs[3+si];
      const float* src = w2 + ((size_t)(si*256 + j))*256 + k0;
      v8h o;
      #pragma unroll
      for (int e=0;e<8;++e){
        float qv = rintf(src[e]*inv);
        qv = fminf(fmaxf(qv,-128.f),127.f);
        o[e] = (_Float16)qv;
      }
      w2F[r] = o;
    } else if (i < NFT){
      int r = i - NF1 - NF2;
      int lane = r & 63; int rest = r >> 6;
      int q = rest & 7; int rc = rest >> 3;
      int ct = rc % 11; int si = rc / 11;
      int j = ct*16 + (lane&15);
      int nout = (si==1)?125:165;
      const float* w3 = (si==0)?w30:((si==1)?w31:w32);
      int k0 = q*32 + 8*(lane>>4);
      float inv = 1.f/qs[6+si];
      v8h o;
      #pragma unroll
      for (int e=0;e<8;++e){
        float wv = (j<nout)? w3[(size_t)j*256 + k0+e] : 0.f;
        float qv = rintf(wv*inv);
        qv = fminf(fmaxf(qv,-128.f),127.f);
        o[e] = (_Float16)qv;
      }
      w3F[r] = o;
    }
    return;
  }
  // ---- GRU proper: 8 waves, wave w owns cells [w*32, w*32+32) as 6 n-tiles ----
  int a = blk>>1, d = blk&1;
  int si = (a<15)?0:((a<55)?1:2);
  int sd = si*2+d;
  int w = tid>>6, lane = tid&63;
  int g16 = lane>>4;
  int ct = g16 & 1;

  __shared__ int ord_s[MAXT];
  __shared__ alignas(16) signed char h8[2][DD];

  ord_s[tid] = order[a*MAXT + tid];
  if (tid < DD) h8[0][tid] = 0;

  int cnt = cnteff[2*a], eff = cnteff[2*a+1];

  int c = w*32 + (lane&31);                 // this lane's cell
  float bn = bhh[sd*G3 + 2*DD + c];
  const float ISQ = 1.f/(127.f*127.f);
  float sr = cm[sd*G3 +        c]*ISQ;
  float sz = cm[sd*G3 + 256 +  c]*ISQ;
  float sn = cm[sd*G3 + 512 +  c]*ISQ;

  // B fragments: 24 x v4i = 96 dwords resident
  v4i bf[6][4];
  {
    const v4i* wp = whhB8 + (((size_t)sd*8 + w)*64 + lane)*24;
    #pragma unroll
    for (int nt=0;nt<6;++nt)
      #pragma unroll
      for (int q=0;q<4;++q)
        bf[nt][q] = wp[nt*4+q];
  }

  const uint2* Eb = reinterpret_cast<const uint2*>(E) + (size_t)sd*NNP*256;

  // RACE FIX: barrier BEFORE any read of ord_s (writer of ord_s[idx0] is
  // usually a different wave; pre-barrier read -> wild E address).
  __syncthreads();

  float h = 0.f;
  uint2 gEven, gOdd;
  {
    int idx0 = d ? (eff-1) : 0;
    int n0 = (idx0 < cnt) ? ord_s[idx0] : NN;
    gEven = Eb[(size_t)n0*256 + c];
  }

  for (int t=0;t<eff;++t){
    int p = t & 1;
    if (t+1 < eff){
      int idx1 = d ? (eff-2-t) : (t+1);
      int n1 = (idx1 < cnt) ? ord_s[idx1] : NN;
      if (p==0) gOdd  = Eb[(size_t)n1*256 + c];
      else      gEven = Eb[(size_t)n1*256 + c];
    }
    v4i acc0={0,0,0,0}, acc1={0,0,0,0}, acc2={0,0,0,0};
    v4i acc3={0,0,0,0}, acc4={0,0,0,0}, acc5={0,0,0,0};
    #pragma unroll
    for (int q=0;q<4;++q){
      v4i af = *reinterpret_cast<const v4i*>(&h8[p][64*q + 16*g16]);
      acc0 = __builtin_amdgcn_mfma_i32_16x16x64_i8(af, bf[0][q], acc0, 0,0,0);
      acc1 = __builtin_amdgcn_mfma_i32_16x16x64_i8(af, bf[1][q], acc1, 0,0,0);
      acc2 = __builtin_amdgcn_mfma_i32_16x16x64_i8(af, bf[2][q], acc2, 0,0,0);
      acc3 = __builtin_amdgcn_mfma_i32_16x16x64_i8(af, bf[3][q], acc3, 0,0,0);
      acc4 = __builtin_amdgcn_mfma_i32_16x16x64_i8(af, bf[4][q], acc4, 0,0,0);
      acc5 = __builtin_amdgcn_mfma_i32_16x16x64_i8(af, bf[5][q], acc5, 0,0,0);
    }
    v4h ev = __builtin_bit_cast(v4h, (p==0) ? gEven : gOdd);
    int ir  = (ct==0) ? acc0[0] : acc1[0];
    int iz  = (ct==0) ? acc2[0] : acc3[0];
    int inn = (ct==0) ? acc4[0] : acc5[0];
    float r  = sigf((float)ev[0] + (float)ir*sr);
    float z  = sigf((float)ev[1] + (float)iz*sz);
    float nv = tanhf_fast((float)ev[2] + r*((float)inn*sn + bn));
    h = z*(h - nv) + nv;
    if (lane < 32) h8[p^1][c] = (signed char)(int)rintf(h*127.f);
    __syncthreads();
  }
  if (lane < 32) hout[(size_t)(2*a+d)*DD + c] = h;
}

// ================= MLP via MFMA fp16, pre-packed quantized fragments =================
__global__ __launch_bounds__(512) void mlp_kernel(
    const float* __restrict__ hout, const float* __restrict__ abn,
    const float* __restrict__ anchors, const float* __restrict__ audio_len,
    const v8h* __restrict__ w1F, const v8h* __restrict__ w2F, const v8h* __restrict__ w3F,
    const float* __restrict__ qs,
    const float* __restrict__ sw0, const float* __restrict__ ew0,
    const float* __restrict__ sw1, const float* __restrict__ ew1,
    const float* __restrict__ sw2, const float* __restrict__ ew2,
    float* __restrict__ out){
  int bm = blockIdx.x;
  int si = (bm==0)?0:((bm<4)?1:2);
  int mt = (bm==0)?0:((bm<4)?(bm-1):0);
  int cntA = (si==1)?40:15;
  int offA = (si==0)?0:((si==1)?15:55);
  int bb   = (si==1)?60:80;
  int m0 = mt*16;
  const float* sw = (si==0)?sw0:((si==1)?sw1:sw2);
  const float* ew = (si==0)?ew0:((si==1)?ew1:ew2);
  float al = audio_len[0];

  __shared__ _Float16 feat[16][552];
  __shared__ _Float16 h1s[16][264];
  __shared__ float    os[16][184];

  int tid = threadIdx.x;
  int lane = tid & 63, wv = tid >> 6;
  int l15 = lane & 15, g16 = lane >> 4;

  for (int idx = tid; idx < 16*552; idx += 512){
    int r = idx / 552, c2 = idx - r*552;
    float v = 0.f;
    int m = m0 + r;
    if (m < cntA){
      int a = offA + m;
      if (c2 < 256)       v = hout[(size_t)(2*a)*DD + c2];
      else if (c2 < 512)  v = hout[(size_t)(2*a+1)*DD + (c2-256)];
      else if (c2 == 512) v = abn[m];
      else if (c2 == 513){ float s=anchors[2*a], e=anchors[2*a+1]; v = (s+e)*0.5f/al; }
      else if (c2 == 514){ float s=anchors[2*a], e=anchors[2*a+1]; v = (e-s)/al; }
    }
    feat[r][c2] = (_Float16)v;
  }
  __syncthreads();
  float sc1 = qs[si], sc2 = qs[3+si], sc3 = qs[6+si];

  // Layer 1: K=544 (17 kq), N=256
  for (int nt = wv; nt < 16; nt += 8){
    int j = nt*16 + l15;
    const v8h* bp = w1F + (size_t)(si*16 + nt)*17*64 + lane;
    v4f acc = {0.f,0.f,0.f,0.f};
    for (int kq = 0; kq < 17; ++kq){
      v8h af = *reinterpret_cast<const v8h*>(&feat[l15][kq*32 + 8*g16]);
      acc = __builtin_amdgcn_mfma_f32_16x16x32_f16(af, bp[kq*64], acc, 0,0,0);
    }
    #pragma unroll
    for (int r=0;r<4;++r) h1s[g16*4+r][j] = (_Float16)fmaxf(acc[r]*sc1, 0.f);
  }
  __syncthreads();
  // Layer 2: K=256, N=256
  for (int nt = wv; nt < 16; nt += 8){
    int j = nt*16 + l15;
    const v8h* bp = w2F + (size_t)(si*16 + nt)*8*64 + lane;
    v4f acc = {0.f,0.f,0.f,0.f};
    for (int kq = 0; kq < 8; ++kq){
      v8h af = *reinterpret_cast<const v8h*>(&h1s[l15][kq*32 + 8*g16]);
      acc = __builtin_amdgcn_mfma_f32_16x16x32_f16(af, bp[kq*64], acc, 0,0,0);
    }
    #pragma unroll
    for (int r=0;r<4;++r) feat[g16*4+r][j] = (_Float16)fmaxf(acc[r]*sc2, 0.f);
  }
  __syncthreads();
  // Layer 3: K=256, N=176
  for (int nt = wv; nt < 11; nt += 8){
    int j = nt*16 + l15;
    const v8h* bp = w3F + (size_t)(si*11 + nt)*8*64 + lane;
    v4f acc = {0.f,0.f,0.f,0.f};
    for (int kq = 0; kq < 8; ++kq){
      v8h af = *reinterpret_cast<const v8h*>(&feat[l15][kq*32 + 8*g16]);
      acc = __builtin_amdgcn_mfma_f32_16x16x32_f16(af, bp[kq*64], acc, 0,0,0);
    }
    #pragma unroll
    for (int r=0;r<4;++r) os[g16*4+r][j] = acc[r]*sc3;
  }
  __syncthreads();
  // Head: one wave per anchor
  for (int lm = wv; lm < 16; lm += 8){
    int m = m0 + lm;
    if (m >= cntA) continue;
    int a = offA + m;
    float s = anchors[2*a], e = anchors[2*a+1];
    float x0 = (lane < bb) ? os[lm][lane] : -1e30f;
    float x1 = (lane+64 < bb) ? os[lm][lane+64] : -1e30f;
    float mx = fmaxf(x0, x1);
    #pragma unroll
    for (int sh=1; sh<64; sh<<=1) mx = fmaxf(mx, __shfl_xor(mx, sh));
    float e0 = (lane < bb) ? expf(x0-mx) : 0.f;
    float e1 = (lane+64 < bb) ? expf(x1-mx) : 0.f;
    float se = e0 + e1;
    float ws2 = e0*((lane<bb)?sw[lane]:0.f) + e1*((lane+64<bb)?sw[lane+64]:0.f);
    #pragma unroll
    for (int sh=1; sh<64; sh<<=1){ se += __shfl_xor(se, sh); ws2 += __shfl_xor(ws2, sh); }
    float so = ws2/se;
    float y0 = (lane < bb) ? os[lm][bb+lane] : -1e30f;
    float y1 = (lane+64 < bb) ? os[lm][bb+lane+64] : -1e30f;
    float my = fmaxf(y0, y1);
    #pragma unroll
    for (int sh=1; sh<64; sh<<=1) my = fmaxf(my, __shfl_xor(my, sh));
    float f0 = (lane < bb) ? expf(y0-my) : 0.f;
    float f1 = (lane+64 < bb) ? expf(y1-my) : 0.f;
    float sf = f0 + f1;
    float wf = f0*((lane<bb)?ew[lane]:0.f) + f1*((lane+64<bb)?ew[lane+64]:0.f);
    #pragma unroll
    for (int sh=1; sh<64; sh<<=1){ sf += __shfl_xor(sf, sh); wf += __shfl_xor(wf, sh); }
    float eo = wf/sf;
    if (lane == 0){
      out[2*a]   = fminf(fmaxf(s+so, 0.f), al);
      out[2*a+1] = fminf(fmaxf(e+eo, 0.f), al);
      out[140+a] = os[lm][2*bb];
    }
    if (lane < 4) out[210+4*a+lane] = os[lm][2*bb+1+lane];
  }
}

extern "C" void kernel_launch(void* const* d_in, const int* in_sizes, int n_in,
                              void* d_out, int out_size, void* d_ws, size_t ws_size,
                              hipStream_t stream){
  const float* emb   = (const float*)d_in[0];
  const float* tpin  = (const float*)d_in[1];
  const float* npred = (const float*)d_in[2];
  const float* alen  = (const float*)d_in[3];
  const float* anch  = (const float*)d_in[4];
  const float* wih   = (const float*)d_in[5];
  const float* whh   = (const float*)d_in[6];
  const float* bih   = (const float*)d_in[7];
  const float* bhh   = (const float*)d_in[8];
  const float* w1    = (const float*)d_in[9];
  const float* w2    = (const float*)d_in[10];
  const float* w30   = (const float*)d_in[11];
  const float* w31   = (const float*)d_in[12];
  const float* w32   = (const float*)d_in[13];
  const float* sw0   = (const float*)d_in[14];
  const float* ew0   = (const float*)d_in[15];
  const float* sw1   = (const float*)d_in[16];
  const float* ew1   = (const float*)d_in[17];
  const float* sw2   = (const float*)d_in[18];
  const float* ew2   = (const float*)d_in[19];

  char* ws = (char*)d_ws;
  size_t off = 0;
  auto take = [&](size_t bytes)->char*{
    char* p = ws + off;
    off = (off + bytes + 255) & ~(size_t)255;
    return p;
  };
  float* abn    = (float*)take((size_t)NN*4);
  int*   order_ = (int*)  take((size_t)NA*MAXT*4);
  int*   cnteff = (int*)  take((size_t)NA*2*4);
  float* qs     = (float*)take(16*4);
  float* cm     = (float*)take((size_t)6*G3*4);
  uint4* whhB8  = (uint4*)take((size_t)6*8*1536*16);
  _Float16* E   = (_Float16*)take((size_t)6*NNP*1024*2);
  float* hout   = (float*)take((size_t)NA*2*DD*4);
  v8h* w1F      = (v8h*)take((size_t)NF1*16);
  v8h* w2F      = (v8h*)take((size_t)NF2*16);
  v8h* w3F      = (v8h*)take((size_t)NF3*16);
  (void)ws_size; (void)in_sizes; (void)n_in; (void)out_size;

  mega_kernel<<<dim3(4757), dim3(256), 0, stream>>>(npred, tpin, alen, anch, whh, wih, emb,
                                                    bih, bhh, w1, w2, w30, w31, w32,
                                                    abn, order_, cnteff, qs, cm, whhB8, E);
  {
    const int packBlocks = (NFT + 511)/512;   // 183
    gru_kernel<<<dim3(NA*2 + packBlocks), dim3(512), 0, stream>>>(
        E, (const v4i*)whhB8, bhh, cm, order_, cnteff, hout,
        w1, w2, w30, w31, w32, qs, w1F, w2F, w3F);
  }
  mlp_kernel<<<dim3(5), dim3(512), 0, stream>>>(hout, abn, anch, alen, w1F, w2F, w3F, qs,
                                                sw0, ew0, sw1, ew1, sw2, ew2, (float*)d_out);
}

// Round 14
// 371.767 us; speedup vs baseline: 1.3676x; 1.0463x over previous
//
#include <hip/hip_runtime.h>
#include <math.h>

#define NN 1024
#define NNP 1025
#define DD 256
#define CC 5
#define G3 768
#define MAXT 512
#define NA 70

typedef _Float16 v8h __attribute__((ext_vector_type(8)));
typedef _Float16 v4h __attribute__((ext_vector_type(4)));
typedef float v4f __attribute__((ext_vector_type(4)));
typedef int v4i __attribute__((ext_vector_type(4)));

#define NF1 (3*16*17*64)
#define NF2 (3*16*8*64)
#define NF3 (3*11*8*64)
#define NFT (NF1+NF2+NF3)

__device__ __forceinline__ float sigf(float x){ return __fdividef(1.f, 1.f + __expf(-x)); }
__device__ __forceinline__ float tanhf_fast(float x){ return 1.f - __fdividef(2.f, __expf(2.f*x) + 1.f); }

// ================= MEGA kernel =================
// [0,4) abn ; [4,74) order ; [74,83) qs absmax ; [83,101) E bias row
// [101,149) whh colmax + int8 frags per (sd, w8)
// [149,725) E-GEMM: block = (sd, colgroup, rowoctet); B register-resident, 8 row-tiles
__global__ __launch_bounds__(256) void mega_kernel(
    const float* __restrict__ node_pred, const float* __restrict__ tp_in,
    const float* __restrict__ audio_len, const float* __restrict__ anchors,
    const float* __restrict__ whh, const float* __restrict__ wih,
    const float* __restrict__ emb,
    const float* __restrict__ bih, const float* __restrict__ bhh,
    const float* __restrict__ w1, const float* __restrict__ w2,
    const float* __restrict__ w30, const float* __restrict__ w31, const float* __restrict__ w32,
    float* __restrict__ abn, int* __restrict__ order, int* __restrict__ cnteff,
    float* __restrict__ qs, float* __restrict__ cm,
    uint4* __restrict__ whhB8, _Float16* __restrict__ E){
  __shared__ __align__(16) unsigned char smem[16*264*2];
  int b = blockIdx.x, tid = threadIdx.x;
  if (b < 4){
    int i = b*256 + tid;
    float pv[CC]; float m = -1e30f;
    for (int c=0;c<CC;++c){ pv[c]=node_pred[i*CC+c]; m=fmaxf(m,pv[c]); }
    float s=0.f;
    for (int c=0;c<CC;++c) s += expf(pv[c]-m);
    abn[i] = expf(pv[0]-m)/s;
  } else if (b < 74){
    if (tid >= 64) return;
    int a = b-4; int lane = tid;
    float al = audio_len[0];
    float s = anchors[2*a], e = anchors[2*a+1];
    int* ord = order + a*MAXT;
    int cnt = 0;
    for (int base=0; base<NN; base+=64){
      float tp = tp_in[base+lane]*al;
      bool msk = (tp>=s)&&(tp<=e);
      unsigned long long bal = __ballot(msk);
      int off = (int)__popcll(bal & ((1ull<<lane)-1ull));
      if (msk && (cnt+off)<MAXT) ord[cnt+off] = base+lane;
      cnt += (int)__popcll(bal);
    }
    if (lane==0){ int c = cnt<MAXT?cnt:MAXT; cnteff[2*a]=c; cnteff[2*a+1]=(c>0)?c:1; }
  } else if (b < 83){
    int m = b-74;
    const float* p; int n;
    if (m<3){ p = w1 + (size_t)m*256*519; n = 256*519; }
    else if (m<6){ p = w2 + (size_t)(m-3)*256*256; n = 256*256; }
    else { p = (m==6)?w30:((m==7)?w31:w32); n = ((m==7)?125:165)*256; }
    float mx = 0.f;
    for (int i=tid;i<n;i+=256) mx = fmaxf(mx, fabsf(p[i]));
    float* red = (float*)smem;
    red[tid]=mx; __syncthreads();
    for (int sft=128; sft>0; sft>>=1){ if (tid<sft) red[tid]=fmaxf(red[tid],red[tid+sft]); __syncthreads(); }
    if (tid==0) qs[m] = fmaxf(red[0]/127.f, 1e-8f);
  } else if (b < 101){
    int i = (b-83)*256 + tid;
    if (i >= 4608) return;
    int gt = i % 3; int c = (i/3)&255; int sd = i/768;
    int j = gt*256 + c;
    float v = bih[sd*G3+j] + ((gt<2)? bhh[sd*G3+j] : 0.f);
    E[((size_t)(sd*NNP + NN))*1024 + c*4 + gt] = (_Float16)v;
  } else if (b < 149){
    // whh colmax + int8 fragment pack per (sd, w), 8-wave gru layout (6 n-tiles)
    int bb = b-101;
    int sd = bb>>3, w = bb&7;
    float* cm_lds = (float*)smem;         // 96 floats
    int lane = tid & 63, wv = tid >> 6;
    for (int it=0; it<24; ++it){
      int lr = it*4 + wv;                 // 0..95
      int gt = lr>>5, c = lr&31;
      int j = gt*256 + w*32 + c;
      float4 v = reinterpret_cast<const float4*>(whh + ((size_t)sd*G3 + j)*DD)[lane];
      float mx = fmaxf(fmaxf(fabsf(v.x),fabsf(v.y)), fmaxf(fabsf(v.z),fabsf(v.w)));
      #pragma unroll
      for (int sh=1; sh<64; sh<<=1) mx = fmaxf(mx, __shfl_xor(mx, sh));
      if (lane==0){
        float cmax = fmaxf(mx, 1e-12f);
        cm_lds[lr] = cmax;
        cm[sd*G3 + j] = cmax;
      }
    }
    __syncthreads();
    #pragma unroll
    for (int ee=0; ee<6; ++ee){
      int il = tid*6 + ee;                // 0..1535 = lane2*24 + nt*4 + q
      int q    = il & 3;
      int nt   = (il>>2) % 6;
      int lane2= il / 24;
      int gt = nt>>1, half = nt&1;
      int j  = gt*256 + w*32 + half*16 + (lane2&15);
      int lr = gt*32  + half*16 + (lane2&15);
      int kbase = 64*q + 16*(lane2>>4);
      float inv = 127.f/cm_lds[lr];
      const float* src = whh + ((size_t)sd*G3 + j)*DD + kbase;
      unsigned int dw[4];
      #pragma unroll
      for (int d2=0; d2<4; ++d2){
        unsigned int acc = 0;
        #pragma unroll
        for (int e2=0; e2<4; ++e2){
          float qv = rintf(src[4*d2+e2]*inv);
          qv = fminf(fmaxf(qv,-127.f),127.f);
          int iq = (int)qv;
          acc |= ((unsigned int)(iq & 255)) << (8*e2);
        }
        dw[d2] = acc;
      }
      uint4 v; v.x=dw[0]; v.y=dw[1]; v.z=dw[2]; v.w=dw[3];
      whhB8[(size_t)(sd*8 + w)*1536 + il] = v;
    }
  } else {
    // E-GEMM: block = (sd, colgroup cg, rowoctet rq). B fp16 fragments live in
    // registers (converted once); loop 8 row-tiles staging A in LDS.
    typedef _Float16 AsT[264];
    AsT* As = (AsT*)smem;
    int b2 = b - 149;                    // 0..575
    int sd = b2 / 96;
    int rem = b2 - sd*96;
    int cg = rem >> 3, rq = rem & 7;
    int lane = tid & 63, wv = tid >> 6;
    int l15 = lane & 15, g16 = lane >> 4;
    int c_t = cg*4 + wv;
    int j = c_t*16 + l15;
    const float* Bp = wih + ((size_t)sd*G3 + j)*DD + 8*g16;
    float bsum = bih[sd*G3 + j] + (((j>>8) < 2) ? bhh[sd*G3 + j] : 0.f);
    v8h bf[8];
    #pragma unroll
    for (int q=0;q<8;++q){
      float4 b0 = *reinterpret_cast<const float4*>(Bp + 32*q);
      float4 b1 = *reinterpret_cast<const float4*>(Bp + 32*q + 4);
      v8h o;
      o[0]=(_Float16)b0.x; o[1]=(_Float16)b0.y; o[2]=(_Float16)b0.z; o[3]=(_Float16)b0.w;
      o[4]=(_Float16)b1.x; o[5]=(_Float16)b1.y; o[6]=(_Float16)b1.z; o[7]=(_Float16)b1.w;
      bf[q] = o;
    }
    int gt = j>>8, cc = j&255;
    for (int rt8=0; rt8<8; ++rt8){
      int row0 = (rq*8 + rt8)*16;
      {
        int rr = tid>>4, k0 = (tid&15)*16;
        const float4* ep = reinterpret_cast<const float4*>(emb + (size_t)(row0+rr)*DD + k0);
        #pragma unroll
        for (int f=0; f<4; ++f){
          float4 v = ep[f];
          v4h o; o[0]=(_Float16)v.x; o[1]=(_Float16)v.y; o[2]=(_Float16)v.z; o[3]=(_Float16)v.w;
          *reinterpret_cast<v4h*>(&As[rr][k0 + f*4]) = o;
        }
      }
      __syncthreads();
      v4f acc = {0.f,0.f,0.f,0.f};
      #pragma unroll
      for (int q=0;q<8;++q){
        v8h af = *reinterpret_cast<const v8h*>(&As[l15][32*q + 8*g16]);
        acc = __builtin_amdgcn_mfma_f32_16x16x32_f16(af, bf[q], acc, 0,0,0);
      }
      #pragma unroll
      for (int r=0;r<4;++r){
        int row = row0 + g16*4 + r;
        E[((size_t)(sd*NNP + row))*1024 + cc*4 + gt] = (_Float16)(acc[r] + bsum);
      }
      __syncthreads();
    }
  }
}

// ================= GRU launch: blocks [0,140) GRU (8 waves) ; blocks >=140 MLP frag pack =================
__global__ __launch_bounds__(512, 2) void gru_kernel(
    const _Float16* __restrict__ E, const v4i* __restrict__ whhB8,
    const float* __restrict__ bhh, const float* __restrict__ cm,
    const int* __restrict__ order, const int* __restrict__ cnteff,
    float* __restrict__ hout,
    const float* __restrict__ w1, const float* __restrict__ w2,
    const float* __restrict__ w30, const float* __restrict__ w31, const float* __restrict__ w32,
    const float* __restrict__ qs,
    v8h* __restrict__ w1F, v8h* __restrict__ w2F, v8h* __restrict__ w3F){
  int blk = blockIdx.x;
  int tid = threadIdx.x;
  if (blk >= NA*2){
    int i = (blk - NA*2)*512 + tid;
    if (i < NF1){
      int lane = i & 63; int rest = i >> 6;
      int q = rest % 17; int rc = rest / 17;
      int ct = rc & 15; int si = rc >> 4;
      int j = ct*16 + (lane&15);
      int k0 = q*32 + 8*(lane>>4);
      float inv = 1.f/qs[si];
      const float* src = w1 + ((size_t)(si*256 + j))*519;
      v8h o;
      #pragma unroll
      for (int e=0;e<8;++e){
        int k = k0+e;
        float wv = (k<519)? src[k] : 0.f;
        float qv = rintf(wv*inv);
        qv = fminf(fmaxf(qv,-128.f),127.f);
        o[e] = (_Float16)qv;
      }
      w1F[i] = o;
    } else if (i < NF1+NF2){
      int r = i - NF1;
      int lane = r & 63; int rest = r >> 6;
      int q = rest & 7; int rc = rest >> 3;
      int ct = rc & 15; int si = rc >> 4;
      int j = ct*16 + (lane&15);
      int k0 = q*32 + 8*(lane>>4);
      float inv = 1.f/qs[3+si];
      const float* src = w2 + ((size_t)(si*256 + j))*256 + k0;
      v8h o;
      #pragma unroll
      for (int e=0;e<8;++e){
        float qv = rintf(src[e]*inv);
        qv = fminf(fmaxf(qv,-128.f),127.f);
        o[e] = (_Float16)qv;
      }
      w2F[r] = o;
    } else if (i < NFT){
      int r = i - NF1 - NF2;
      int lane = r & 63; int rest = r >> 6;
      int q = rest & 7; int rc = rest >> 3;
      int ct = rc % 11; int si = rc / 11;
      int j = ct*16 + (lane&15);
      int nout = (si==1)?125:165;
      const float* w3 = (si==0)?w30:((si==1)?w31:w32);
      int k0 = q*32 + 8*(lane>>4);
      float inv = 1.f/qs[6+si];
      v8h o;
      #pragma unroll
      for (int e=0;e<8;++e){
        float wv = (j<nout)? w3[(size_t)j*256 + k0+e] : 0.f;
        float qv = rintf(wv*inv);
        qv = fminf(fmaxf(qv,-128.f),127.f);
        o[e] = (_Float16)qv;
      }
      w3F[r] = o;
    }
    return;
  }
  // ---- GRU proper: 8 waves, wave w owns cells [w*32, w*32+32) as 6 n-tiles ----
  int a = blk>>1, d = blk&1;
  int si = (a<15)?0:((a<55)?1:2);
  int sd = si*2+d;
  int w = tid>>6, lane = tid&63;
  int g16 = lane>>4;
  int ct = g16 & 1;

  __shared__ int ord_s[MAXT];
  __shared__ alignas(16) signed char h8[2][DD];

  ord_s[tid] = order[a*MAXT + tid];
  if (tid < DD) h8[0][tid] = 0;

  int cnt = cnteff[2*a], eff = cnteff[2*a+1];

  int c = w*32 + (lane&31);
  float bn = bhh[sd*G3 + 2*DD + c];
  const float ISQ = 1.f/(127.f*127.f);
  float sr = cm[sd*G3 +        c]*ISQ;
  float sz = cm[sd*G3 + 256 +  c]*ISQ;
  float sn = cm[sd*G3 + 512 +  c]*ISQ;

  v4i bf[6][4];
  {
    const v4i* wp = whhB8 + (((size_t)sd*8 + w)*64 + lane)*24;
    #pragma unroll
    for (int nt=0;nt<6;++nt)
      #pragma unroll
      for (int q=0;q<4;++q)
        bf[nt][q] = wp[nt*4+q];
  }

  const uint2* Eb = reinterpret_cast<const uint2*>(E) + (size_t)sd*NNP*256;

  // RACE FIX: barrier BEFORE any read of ord_s.
  __syncthreads();

  float h = 0.f;
  uint2 gEven, gOdd;
  {
    int idx0 = d ? (eff-1) : 0;
    int n0 = (idx0 < cnt) ? ord_s[idx0] : NN;
    gEven = Eb[(size_t)n0*256 + c];
  }

  for (int t=0;t<eff;++t){
    int p = t & 1;
    if (t+1 < eff){
      int idx1 = d ? (eff-2-t) : (t+1);
      int n1 = (idx1 < cnt) ? ord_s[idx1] : NN;
      if (p==0) gOdd  = Eb[(size_t)n1*256 + c];
      else      gEven = Eb[(size_t)n1*256 + c];
    }
    v4i acc0={0,0,0,0}, acc1={0,0,0,0}, acc2={0,0,0,0};
    v4i acc3={0,0,0,0}, acc4={0,0,0,0}, acc5={0,0,0,0};
    #pragma unroll
    for (int q=0;q<4;++q){
      v4i af = *reinterpret_cast<const v4i*>(&h8[p][64*q + 16*g16]);
      acc0 = __builtin_amdgcn_mfma_i32_16x16x64_i8(af, bf[0][q], acc0, 0,0,0);
      acc1 = __builtin_amdgcn_mfma_i32_16x16x64_i8(af, bf[1][q], acc1, 0,0,0);
      acc2 = __builtin_amdgcn_mfma_i32_16x16x64_i8(af, bf[2][q], acc2, 0,0,0);
      acc3 = __builtin_amdgcn_mfma_i32_16x16x64_i8(af, bf[3][q], acc3, 0,0,0);
      acc4 = __builtin_amdgcn_mfma_i32_16x16x64_i8(af, bf[4][q], acc4, 0,0,0);
      acc5 = __builtin_amdgcn_mfma_i32_16x16x64_i8(af, bf[5][q], acc5, 0,0,0);
    }
    v4h ev = __builtin_bit_cast(v4h, (p==0) ? gEven : gOdd);
    int ir  = (ct==0) ? acc0[0] : acc1[0];
    int iz  = (ct==0) ? acc2[0] : acc3[0];
    int inn = (ct==0) ? acc4[0] : acc5[0];
    float r  = sigf((float)ev[0] + (float)ir*sr);
    float z  = sigf((float)ev[1] + (float)iz*sz);
    float nv = tanhf_fast((float)ev[2] + r*((float)inn*sn + bn));
    h = z*(h - nv) + nv;
    if (lane < 32) h8[p^1][c] = (signed char)(int)rintf(h*127.f);
    __syncthreads();
  }
  if (lane < 32) hout[(size_t)(2*a+d)*DD + c] = h;
}

// ================= MLP via MFMA fp16, pre-packed quantized fragments =================
__global__ __launch_bounds__(512) void mlp_kernel(
    const float* __restrict__ hout, const float* __restrict__ abn,
    const float* __restrict__ anchors, const float* __restrict__ audio_len,
    const v8h* __restrict__ w1F, const v8h* __restrict__ w2F, const v8h* __restrict__ w3F,
    const float* __restrict__ qs,
    const float* __restrict__ sw0, const float* __restrict__ ew0,
    const float* __restrict__ sw1, const float* __restrict__ ew1,
    const float* __restrict__ sw2, const float* __restrict__ ew2,
    float* __restrict__ out){
  int bm = blockIdx.x;
  int si = (bm==0)?0:((bm<4)?1:2);
  int mt = (bm==0)?0:((bm<4)?(bm-1):0);
  int cntA = (si==1)?40:15;
  int offA = (si==0)?0:((si==1)?15:55);
  int bb   = (si==1)?60:80;
  int m0 = mt*16;
  const float* sw = (si==0)?sw0:((si==1)?sw1:sw2);
  const float* ew = (si==0)?ew0:((si==1)?ew1:ew2);
  float al = audio_len[0];

  __shared__ _Float16 feat[16][552];
  __shared__ _Float16 h1s[16][264];
  __shared__ float    os[16][184];

  int tid = threadIdx.x;
  int lane = tid & 63, wv = tid >> 6;
  int l15 = lane & 15, g16 = lane >> 4;

  for (int idx = tid; idx < 16*552; idx += 512){
    int r = idx / 552, c2 = idx - r*552;
    float v = 0.f;
    int m = m0 + r;
    if (m < cntA){
      int a = offA + m;
      if (c2 < 256)       v = hout[(size_t)(2*a)*DD + c2];
      else if (c2 < 512)  v = hout[(size_t)(2*a+1)*DD + (c2-256)];
      else if (c2 == 512) v = abn[m];
      else if (c2 == 513){ float s=anchors[2*a], e=anchors[2*a+1]; v = (s+e)*0.5f/al; }
      else if (c2 == 514){ float s=anchors[2*a], e=anchors[2*a+1]; v = (e-s)/al; }
    }
    feat[r][c2] = (_Float16)v;
  }
  __syncthreads();
  float sc1 = qs[si], sc2 = qs[3+si], sc3 = qs[6+si];

  for (int nt = wv; nt < 16; nt += 8){
    int j = nt*16 + l15;
    const v8h* bp = w1F + (size_t)(si*16 + nt)*17*64 + lane;
    v4f acc = {0.f,0.f,0.f,0.f};
    for (int kq = 0; kq < 17; ++kq){
      v8h af = *reinterpret_cast<const v8h*>(&feat[l15][kq*32 + 8*g16]);
      acc = __builtin_amdgcn_mfma_f32_16x16x32_f16(af, bp[kq*64], acc, 0,0,0);
    }
    #pragma unroll
    for (int r=0;r<4;++r) h1s[g16*4+r][j] = (_Float16)fmaxf(acc[r]*sc1, 0.f);
  }
  __syncthreads();
  for (int nt = wv; nt < 16; nt += 8){
    int j = nt*16 + l15;
    const v8h* bp = w2F + (size_t)(si*16 + nt)*8*64 + lane;
    v4f acc = {0.f,0.f,0.f,0.f};
    for (int kq = 0; kq < 8; ++kq){
      v8h af = *reinterpret_cast<const v8h*>(&h1s[l15][kq*32 + 8*g16]);
      acc = __builtin_amdgcn_mfma_f32_16x16x32_f16(af, bp[kq*64], acc, 0,0,0);
    }
    #pragma unroll
    for (int r=0;r<4;++r) feat[g16*4+r][j] = (_Float16)fmaxf(acc[r]*sc2, 0.f);
  }
  __syncthreads();
  for (int nt = wv; nt < 11; nt += 8){
    int j = nt*16 + l15;
    const v8h* bp = w3F + (size_t)(si*11 + nt)*8*64 + lane;
    v4f acc = {0.f,0.f,0.f,0.f};
    for (int kq = 0; kq < 8; ++kq){
      v8h af = *reinterpret_cast<const v8h*>(&feat[l15][kq*32 + 8*g16]);
      acc = __builtin_amdgcn_mfma_f32_16x16x32_f16(af, bp[kq*64], acc, 0,0,0);
    }
    #pragma unroll
    for (int r=0;r<4;++r) os[g16*4+r][j] = acc[r]*sc3;
  }
  __syncthreads();
  for (int lm = wv; lm < 16; lm += 8){
    int m = m0 + lm;
    if (m >= cntA) continue;
    int a = offA + m;
    float s = anchors[2*a], e = anchors[2*a+1];
    float x0 = (lane < bb) ? os[lm][lane] : -1e30f;
    float x1 = (lane+64 < bb) ? os[lm][lane+64] : -1e30f;
    float mx = fmaxf(x0, x1);
    #pragma unroll
    for (int sh=1; sh<64; sh<<=1) mx = fmaxf(mx, __shfl_xor(mx, sh));
    float e0 = (lane < bb) ? expf(x0-mx) : 0.f;
    float e1 = (lane+64 < bb) ? expf(x1-mx) : 0.f;
    float se = e0 + e1;
    float ws2 = e0*((lane<bb)?sw[lane]:0.f) + e1*((lane+64<bb)?sw[lane+64]:0.f);
    #pragma unroll
    for (int sh=1; sh<64; sh<<=1){ se += __shfl_xor(se, sh); ws2 += __shfl_xor(ws2, sh); }
    float so = ws2/se;
    float y0 = (lane < bb) ? os[lm][bb+lane] : -1e30f;
    float y1 = (lane+64 < bb) ? os[lm][bb+lane+64] : -1e30f;
    float my = fmaxf(y0, y1);
    #pragma unroll
    for (int sh=1; sh<64; sh<<=1) my = fmaxf(my, __shfl_xor(my, sh));
    float f0 = (lane < bb) ? expf(y0-my) : 0.f;
    float f1 = (lane+64 < bb) ? expf(y1-my) : 0.f;
    float sf = f0 + f1;
    float wf = f0*((lane<bb)?ew[lane]:0.f) + f1*((lane+64<bb)?ew[lane+64]:0.f);
    #pragma unroll
    for (int sh=1; sh<64; sh<<=1){ sf += __shfl_xor(sf, sh); wf += __shfl_xor(wf, sh); }
    float eo = wf/sf;
    if (lane == 0){
      out[2*a]   = fminf(fmaxf(s+so, 0.f), al);
      out[2*a+1] = fminf(fmaxf(e+eo, 0.f), al);
      out[140+a] = os[lm][2*bb];
    }
    if (lane < 4) out[210+4*a+lane] = os[lm][2*bb+1+lane];
  }
}

extern "C" void kernel_launch(void* const* d_in, const int* in_sizes, int n_in,
                              void* d_out, int out_size, void* d_ws, size_t ws_size,
                              hipStream_t stream){
  const float* emb   = (const float*)d_in[0];
  const float* tpin  = (const float*)d_in[1];
  const float* npred = (const float*)d_in[2];
  const float* alen  = (const float*)d_in[3];
  const float* anch  = (const float*)d_in[4];
  const float* wih   = (const float*)d_in[5];
  const float* whh   = (const float*)d_in[6];
  const float* bih   = (const float*)d_in[7];
  const float* bhh   = (const float*)d_in[8];
  const float* w1    = (const float*)d_in[9];
  const float* w2    = (const float*)d_in[10];
  const float* w30   = (const float*)d_in[11];
  const float* w31   = (const float*)d_in[12];
  const float* w32   = (const float*)d_in[13];
  const float* sw0   = (const float*)d_in[14];
  const float* ew0   = (const float*)d_in[15];
  const float* sw1   = (const float*)d_in[16];
  const float* ew1   = (const float*)d_in[17];
  const float* sw2   = (const float*)d_in[18];
  const float* ew2   = (const float*)d_in[19];

  char* ws = (char*)d_ws;
  size_t off = 0;
  auto take = [&](size_t bytes)->char*{
    char* p = ws + off;
    off = (off + bytes + 255) & ~(size_t)255;
    return p;
  };
  float* abn    = (float*)take((size_t)NN*4);
  int*   order_ = (int*)  take((size_t)NA*MAXT*4);
  int*   cnteff = (int*)  take((size_t)NA*2*4);
  float* qs     = (float*)take(16*4);
  float* cm     = (float*)take((size_t)6*G3*4);
  uint4* whhB8  = (uint4*)take((size_t)6*8*1536*16);
  _Float16* E   = (_Float16*)take((size_t)6*NNP*1024*2);
  float* hout   = (float*)take((size_t)NA*2*DD*4);
  v8h* w1F      = (v8h*)take((size_t)NF1*16);
  v8h* w2F      = (v8h*)take((size_t)NF2*16);
  v8h* w3F      = (v8h*)take((size_t)NF3*16);
  (void)ws_size; (void)in_sizes; (void)n_in; (void)out_size;

  mega_kernel<<<dim3(725), dim3(256), 0, stream>>>(npred, tpin, alen, anch, whh, wih, emb,
                                                   bih, bhh, w1, w2, w30, w31, w32,
                                                   abn, order_, cnteff, qs, cm, whhB8, E);
  {
    const int packBlocks = (NFT + 511)/512;   // 183
    gru_kernel<<<dim3(NA*2 + packBlocks), dim3(512), 0, stream>>>(
        E, (const v4i*)whhB8, bhh, cm, order_, cnteff, hout,
        w1, w2, w30, w31, w32, qs, w1F, w2F, w3F);
  }
  mlp_kernel<<<dim3(5), dim3(512), 0, stream>>>(hout, abn, anch, alen, w1F, w2F, w3F, qs,
                                                sw0, ew0, sw1, ew1, sw2, ew2, (float*)d_out);
}